// Round 1
// baseline (1409.869 us; speedup 1.0000x reference)
//
#include <hip/hip_runtime.h>
#include <hip/hip_bf16.h>
#include <stdint.h>

using u16 = unsigned short;
using u32 = unsigned int;

#define NB 64
#define TT 128
#define DK 768
#define MC 30

__device__ inline float bf_lo(u32 u){ union{u32 i; float f;} v; v.i = u << 16; return v.f; }
__device__ inline void unpack2(u32 u, float& lo, float& hi){
  union{u32 i; float f;} a, b; a.i = u << 16; b.i = u & 0xFFFF0000u; lo = a.f; hi = b.f;
}
__device__ inline float bf2f(u16 u){ union{u32 i; float f;} v; v.i = ((u32)u) << 16; return v.f; }
__device__ inline u16 f2bf(float f){
  union{u32 i; float f;} v; v.f = f;
  u32 r = v.i + 0x7FFFu + ((v.i >> 16) & 1u);
  return (u16)(r >> 16);
}

// ---------------- kernel 1: row sums of squares ----------------
__global__ __launch_bounds__(256) void row_norms_k(const float* __restrict__ q, const float* __restrict__ k,
                                                   float* __restrict__ qq, float* __restrict__ kk){
  int wave = blockIdx.x * 4 + (threadIdx.x >> 6);
  int lane = threadIdx.x & 63;
  const float* src; float* dst; int row;
  if (wave < NB * TT) { src = q; dst = qq; row = wave; }
  else                { src = k; dst = kk; row = wave - NB * TT; }
  const float4* p = (const float4*)(src + (size_t)row * DK + lane * 12);
  float s = 0.f;
  #pragma unroll
  for (int t = 0; t < 3; ++t){ float4 v = p[t]; s += v.x*v.x + v.y*v.y + v.z*v.z + v.w*v.w; }
  #pragma unroll
  for (int o = 32; o; o >>= 1) s += __shfl_xor(s, o);
  if (lane == 0) dst[row] = s;
}

// ---------------- kernel 2: cdist GEMM + P + mask ----------------
#define KC 64
__global__ __launch_bounds__(256) void cdist_k(const float* __restrict__ Q, const float* __restrict__ K,
    const float* __restrict__ qq, const float* __restrict__ kk,
    const int* __restrict__ qlen, const int* __restrict__ klen,
    const float* __restrict__ qR, const float* __restrict__ kR,
    float* __restrict__ Dout, u16* __restrict__ inb){
  __shared__ float As[KC][36];
  __shared__ float Bs[KC][132];
  int b  = blockIdx.y;
  int r0 = blockIdx.x * 32;
  int tid = threadIdx.x;
  const float* Qb = Q + ((size_t)b * TT + r0) * DK;
  const float* Kb = K + (size_t)b * TT * DK;
  float acc[4][4] = {};
  for (int kc = 0; kc < DK; kc += KC){
    __syncthreads();
    #pragma unroll
    for (int t = 0; t < 2; ++t){
      int id = tid + t * 256; int row = id >> 4; int k4 = (id & 15) * 4;
      float4 v = *(const float4*)&Qb[(size_t)row * DK + kc + k4];
      As[k4+0][row] = v.x; As[k4+1][row] = v.y; As[k4+2][row] = v.z; As[k4+3][row] = v.w;
    }
    #pragma unroll
    for (int t = 0; t < 8; ++t){
      int id = tid + t * 256; int row = id >> 4; int k4 = (id & 15) * 4;
      float4 v = *(const float4*)&Kb[(size_t)row * DK + kc + k4];
      Bs[k4+0][row] = v.x; Bs[k4+1][row] = v.y; Bs[k4+2][row] = v.z; Bs[k4+3][row] = v.w;
    }
    __syncthreads();
    int r = tid >> 5, cg = tid & 31;
    #pragma unroll 8
    for (int kx = 0; kx < KC; ++kx){
      float4 a  = *(const float4*)&As[kx][r * 4];
      float4 bv = *(const float4*)&Bs[kx][cg * 4];
      float af[4] = {a.x, a.y, a.z, a.w};
      float bf[4] = {bv.x, bv.y, bv.z, bv.w};
      #pragma unroll
      for (int ri = 0; ri < 4; ++ri)
        #pragma unroll
        for (int ci = 0; ci < 4; ++ci)
          acc[ri][ci] = fmaf(af[ri], bf[ci], acc[ri][ci]);
    }
  }
  int r = tid >> 5, cg = tid & 31;
  int ql = qlen[b], kl = klen[b];
  #pragma unroll
  for (int ri = 0; ri < 4; ++ri){
    int row = r0 + r * 4 + ri;
    float qv = qq[b * TT + row];
    float qr = qR[b * TT + row];
    bool rm = row < ql;
    #pragma unroll
    for (int ci = 0; ci < 4; ++ci){
      int col = cg * 4 + ci;
      float kv = kk[b * TT + col];
      float sq = qv + kv - 2.f * acc[ri][ci];
      float d = sqrtf(fmaxf(sq, 1e-12f));
      bool m = rm && (col < kl);
      float dm = m ? d : 0.f;
      float pm = m ? fabsf(qr - kR[b * TT + col]) : 0.f;
      size_t o = ((size_t)b * TT + row) * TT + col;
      Dout[o] = dm;
      inb[((size_t)b * 2 + 0) * (TT*TT) + row * TT + col] = f2bf(dm);
      inb[((size_t)b * 2 + 1) * (TT*TT) + row * TT + col] = f2bf(pm);
    }
  }
}

// ---------------- kernels 3/4: 5x5 conv + relu (templated on CIN) ----------------
// block: 32x16 px tile, 8 out-channels; thread: 2 oc x 8 px
template<int CIN>
__global__ __launch_bounds__(256) void conv5x5_k(const u16* __restrict__ in, const float* __restrict__ wgt,
                                                 const float* __restrict__ bias, u16* __restrict__ out){
  __shared__ u16 in_lds[CIN * 20 * 40];
  __shared__ u16 w_lds[8 * CIN * 32];
  int tile = blockIdx.x, ocg = blockIdx.y, bb = blockIdx.z;
  int x0 = (tile & 3) * 32, y0 = (tile >> 2) * 16;
  int tid = threadIdx.x;
  for (int idx = tid; idx < CIN * 20 * 36; idx += 256){
    int c = idx / 720; int rem = idx - c * 720; int ly = rem / 36; int lx = rem - ly * 36;
    int gy = y0 - 2 + ly, gx = x0 - 2 + lx;
    u16 v = 0;
    if (gy >= 0 && gy < TT && gx >= 0 && gx < TT)
      v = in[((size_t)(bb * CIN + c) << 14) + (gy << 7) + gx];
    in_lds[(c * 20 + ly) * 40 + lx] = v;
  }
  for (int idx = tid; idx < 8 * CIN * 32; idx += 256){
    int k = idx & 31; int rest = idx >> 5; int c = rest % CIN; int o8 = rest / CIN;
    int oc = ocg * 8 + o8;
    float wv = 0.f;
    if (k < 25 && oc < MC) wv = wgt[(oc * CIN + c) * 25 + k];
    w_lds[idx] = f2bf(wv);
  }
  __syncthreads();
  int tx = tid & 3, ty = (tid >> 2) & 15, og = tid >> 6;
  int oc0 = ocg * 8 + og * 2;
  float acc[2][8];
  #pragma unroll
  for (int o = 0; o < 2; ++o){
    float bv = (oc0 + o < MC) ? bias[oc0 + o] : 0.f;
    #pragma unroll
    for (int p = 0; p < 8; ++p) acc[o][p] = bv;
  }
  for (int c = 0; c < CIN; ++c){
    float wr[2][25];
    #pragma unroll
    for (int o = 0; o < 2; ++o){
      const u32* wp = (const u32*)&w_lds[((og * 2 + o) * CIN + c) << 5];
      #pragma unroll
      for (int t = 0; t < 12; ++t) unpack2(wp[t], wr[o][2*t], wr[o][2*t+1]);
      wr[o][24] = bf_lo(wp[12]);
    }
    #pragma unroll
    for (int dy = 0; dy < 5; ++dy){
      const u32* ip = (const u32*)&in_lds[(c * 20 + ty + dy) * 40 + tx * 8];
      float x[12];
      #pragma unroll
      for (int t = 0; t < 6; ++t) unpack2(ip[t], x[2*t], x[2*t+1]);
      #pragma unroll
      for (int dx = 0; dx < 5; ++dx){
        #pragma unroll
        for (int p = 0; p < 8; ++p){
          acc[0][p] = fmaf(x[dx + p], wr[0][dy * 5 + dx], acc[0][p]);
          acc[1][p] = fmaf(x[dx + p], wr[1][dy * 5 + dx], acc[1][p]);
        }
      }
    }
  }
  #pragma unroll
  for (int o = 0; o < 2; ++o){
    int oc = oc0 + o;
    if (oc < MC){
      u32 pack[4];
      #pragma unroll
      for (int t = 0; t < 4; ++t){
        u16 lo = f2bf(fmaxf(acc[o][2*t],   0.f));
        u16 hi = f2bf(fmaxf(acc[o][2*t+1], 0.f));
        pack[t] = (u32)lo | ((u32)hi << 16);
      }
      *(uint4*)&out[((size_t)(bb * MC + oc) << 14) + ((y0 + ty) << 7) + x0 + tx * 8] = *(const uint4*)pack;
    }
  }
}

// ---------------- kernel 5: conv3 + mask + row softmax + A write + row D·A ----------------
__global__ __launch_bounds__(128) void conv3_softmax_k(const u16* __restrict__ act2, const float* __restrict__ w3,
    const float* __restrict__ b3, const float* __restrict__ Dbuf,
    const int* __restrict__ qlen, const int* __restrict__ klen,
    float* __restrict__ Aout, float* __restrict__ rowsum, int b0){
  __shared__ u16 in_lds[MC * 3 * TT];
  __shared__ float wlds[270];
  __shared__ float redm[2], reds[2], redd[2];
  int bb = blockIdx.x >> 7;
  int i  = blockIdx.x & 127;
  int b  = b0 + bb;
  int tid = threadIdx.x;
  for (int idx = tid; idx < MC * 3 * 16; idx += 128){
    int c = idx / 48; int rem = idx - c * 48; int dy = rem >> 4; int g = rem & 15;
    int gy = i - 1 + dy;
    uint4 v = make_uint4(0, 0, 0, 0);
    if (gy >= 0 && gy < TT)
      v = *(const uint4*)&act2[((size_t)(bb * MC + c) << 14) + (gy << 7) + g * 8];
    *(uint4*)&in_lds[(c * 3 + dy) * TT + g * 8] = v;
  }
  for (int idx = tid; idx < 270; idx += 128) wlds[idx] = w3[idx];
  __syncthreads();
  int j = tid;
  float acc = b3[0];
  #pragma unroll 5
  for (int c = 0; c < MC; ++c){
    #pragma unroll
    for (int dy = 0; dy < 3; ++dy){
      int base = (c * 3 + dy) * TT;
      float v0 = (j > 0)   ? bf2f(in_lds[base + j - 1]) : 0.f;
      float v1 =             bf2f(in_lds[base + j]);
      float v2 = (j < 127) ? bf2f(in_lds[base + j + 1]) : 0.f;
      const float* wp = &wlds[c * 9 + dy * 3];
      acc = fmaf(v0, wp[0], acc);
      acc = fmaf(v1, wp[1], acc);
      acc = fmaf(v2, wp[2], acc);
    }
  }
  size_t doff = ((size_t)(b * TT + i) << 7) + j;
  float Dv = Dbuf[doff];
  bool m = (i < qlen[b]) && (j < klen[b]);
  float logit = m ? (acc + Dv) : 100.f;
  float xv = -logit;
  float mx = xv;
  #pragma unroll
  for (int o = 32; o; o >>= 1) mx = fmaxf(mx, __shfl_xor(mx, o));
  if ((tid & 63) == 0) redm[tid >> 6] = mx;
  __syncthreads();
  mx = fmaxf(redm[0], redm[1]);
  float e = __expf(xv - mx);
  float s = e;
  #pragma unroll
  for (int o = 32; o; o >>= 1) s += __shfl_xor(s, o);
  if ((tid & 63) == 0) reds[tid >> 6] = s;
  __syncthreads();
  s = reds[0] + reds[1];
  float a = e / s;
  Aout[doff] = a;
  float rd = Dv * a;
  #pragma unroll
  for (int o = 32; o; o >>= 1) rd += __shfl_xor(rd, o);
  if ((tid & 63) == 0) redd[tid >> 6] = rd;
  __syncthreads();
  if (tid == 0) rowsum[b * TT + i] = redd[0] + redd[1];
}

// ---------------- kernel 6: dis reduce ----------------
__global__ __launch_bounds__(128) void dis_k(const float* __restrict__ rowsum, float* __restrict__ out){
  int b = blockIdx.x, tid = threadIdx.x;
  float v = rowsum[b * TT + tid];
  #pragma unroll
  for (int o = 32; o; o >>= 1) v += __shfl_xor(v, o);
  __shared__ float red[2];
  if ((tid & 63) == 0) red[tid >> 6] = v;
  __syncthreads();
  if (tid == 0) out[b] = (red[0] + red[1]) * (1.0f / 128.0f);
}

extern "C" void kernel_launch(void* const* d_in, const int* in_sizes, int n_in,
                              void* d_out, int out_size, void* d_ws, size_t ws_size,
                              hipStream_t stream){
  const float* q_seq = (const float*)d_in[0];
  const int*   q_len = (const int*)d_in[1];
  const float* q_R   = (const float*)d_in[2];
  const float* k_seq = (const float*)d_in[3];
  const int*   k_len = (const int*)d_in[4];
  const float* k_R   = (const float*)d_in[5];
  const float* c1w   = (const float*)d_in[6];
  const float* c1b   = (const float*)d_in[7];
  const float* c2w   = (const float*)d_in[8];
  const float* c2b   = (const float*)d_in[9];
  const float* c3w   = (const float*)d_in[10];
  const float* c3b   = (const float*)d_in[11];
  float* out = (float*)d_out;

  char* base = (char*)d_ws;
  size_t off = 0;
  auto take = [&](size_t bytes)->char*{
    char* p = base + off;
    off = (off + bytes + 255) & ~(size_t)255;
    return p;
  };
  float* Dbuf   = (float*)take((size_t)NB * TT * TT * 4);
  float* qq     = (float*)take((size_t)NB * TT * 4);
  float* kkn    = (float*)take((size_t)NB * TT * 4);
  float* rowsum = (float*)take((size_t)NB * TT * 4);
  u16*   inb    = (u16*)  take((size_t)NB * 2 * TT * TT * 2);
  size_t fixed = off;
  int BCH = 64;
  while (BCH > 1 && fixed + 2ull * BCH * MC * TT * TT * 2 + 1024 > ws_size) BCH >>= 1;
  u16* act1 = (u16*)take((size_t)BCH * MC * TT * TT * 2);
  u16* act2 = (u16*)take((size_t)BCH * MC * TT * TT * 2);

  row_norms_k<<<4096, 256, 0, stream>>>(q_seq, k_seq, qq, kkn);
  cdist_k<<<dim3(4, NB), 256, 0, stream>>>(q_seq, k_seq, qq, kkn, q_len, k_len, q_R, k_R, Dbuf, inb);
  for (int b0 = 0; b0 < NB; b0 += BCH){
    int nb = BCH;
    conv5x5_k<2><<<dim3(32, 4, nb), 256, 0, stream>>>(inb + (size_t)b0 * 2 * TT * TT, c1w, c1b, act1);
    conv5x5_k<MC><<<dim3(32, 4, nb), 256, 0, stream>>>(act1, c2w, c2b, act2);
    conv3_softmax_k<<<nb * TT, 128, 0, stream>>>(act2, c3w, c3b, Dbuf, q_len, k_len, out, rowsum, b0);
  }
  dis_k<<<NB, 128, 0, stream>>>(rowsum, out + (size_t)NB * TT * TT);
}

// Round 2
// 317.014 us; speedup vs baseline: 4.4473x; 4.4473x over previous
//
#include <hip/hip_runtime.h>
#include <hip/hip_bf16.h>
#include <stdint.h>

using u16 = unsigned short;
using u32 = unsigned int;

#define NB 64
#define TT 128
#define DK 768
#define MC 30

typedef float f32x16 __attribute__((ext_vector_type(16)));
typedef __bf16 bf16x8 __attribute__((ext_vector_type(8)));

__device__ inline void unpack2(u32 u, float& lo, float& hi){
  union{u32 i; float f;} a, b; a.i = u << 16; b.i = u & 0xFFFF0000u; lo = a.f; hi = b.f;
}
__device__ inline float bf2f(u16 u){ union{u32 i; float f;} v; v.i = ((u32)u) << 16; return v.f; }
__device__ inline u16 f2bf(float f){
  union{u32 i; float f;} v; v.f = f;
  u32 r = v.i + 0x7FFFu + ((v.i >> 16) & 1u);
  return (u16)(r >> 16);
}
__device__ inline u32 pack2bf(float a, float b){ return (u32)f2bf(a) | ((u32)f2bf(b) << 16); }

// ---------------- weight prep: swizzled bf16 layouts ----------------
// w2p byte layout: tap*2048 + ((oc*64 + ic*2) ^ ((oc&7)<<4)), oc,ic in [0,32)
// w1p: [c][tap][oc32] plain bf16
__global__ __launch_bounds__(256) void prep_w_k(const float* __restrict__ w2,
    const float* __restrict__ w1, u16* __restrict__ w2p, u16* __restrict__ w1p){
  int bidx = blockIdx.x;
  if (bidx < 25){
    int tap = bidx;
    for (int i = threadIdx.x; i < 1024; i += 256){
      int oc = i >> 5, ic = i & 31;
      float v = (oc < MC && ic < MC) ? w2[(oc*MC + ic)*25 + tap] : 0.f;
      int byteoff = tap*2048 + (((oc<<6) + (ic<<1)) ^ ((oc&7)<<4));
      *(u16*)((char*)w2p + byteoff) = f2bf(v);
    }
  } else {
    for (int i = threadIdx.x; i < 1600; i += 256){
      int oc = i & 31; int t2 = i >> 5; int tap = t2 % 25; int c = t2 / 25;
      float v = (oc < MC) ? w1[(oc*2 + c)*25 + tap] : 0.f;
      w1p[(c*25 + tap)*32 + oc] = f2bf(v);
    }
  }
}

// ---------------- kernel 1: row sums of squares ----------------
__global__ __launch_bounds__(256) void row_norms_k(const float* __restrict__ q, const float* __restrict__ k,
                                                   float* __restrict__ qq, float* __restrict__ kk){
  int wave = blockIdx.x * 4 + (threadIdx.x >> 6);
  int lane = threadIdx.x & 63;
  const float* src; float* dst; int row;
  if (wave < NB * TT) { src = q; dst = qq; row = wave; }
  else                { src = k; dst = kk; row = wave - NB * TT; }
  const float4* p = (const float4*)(src + (size_t)row * DK + lane * 12);
  float s = 0.f;
  #pragma unroll
  for (int t = 0; t < 3; ++t){ float4 v = p[t]; s += v.x*v.x + v.y*v.y + v.z*v.z + v.w*v.w; }
  #pragma unroll
  for (int o = 32; o; o >>= 1) s += __shfl_xor(s, o);
  if (lane == 0) dst[row] = s;
}

// ---------------- kernel 2: cdist GEMM + P + mask ----------------
#define KC 64
__global__ __launch_bounds__(256) void cdist_k(const float* __restrict__ Q, const float* __restrict__ K,
    const float* __restrict__ qq, const float* __restrict__ kk,
    const int* __restrict__ qlen, const int* __restrict__ klen,
    const float* __restrict__ qR, const float* __restrict__ kR,
    float* __restrict__ Dout, u16* __restrict__ inb){
  __shared__ float As[KC][36];
  __shared__ float Bs[KC][132];
  int b  = blockIdx.y;
  int r0 = blockIdx.x * 32;
  int tid = threadIdx.x;
  const float* Qb = Q + ((size_t)b * TT + r0) * DK;
  const float* Kb = K + (size_t)b * TT * DK;
  float acc[4][4] = {};
  for (int kc = 0; kc < DK; kc += KC){
    __syncthreads();
    #pragma unroll
    for (int t = 0; t < 2; ++t){
      int id = tid + t * 256; int row = id >> 4; int k4 = (id & 15) * 4;
      float4 v = *(const float4*)&Qb[(size_t)row * DK + kc + k4];
      As[k4+0][row] = v.x; As[k4+1][row] = v.y; As[k4+2][row] = v.z; As[k4+3][row] = v.w;
    }
    #pragma unroll
    for (int t = 0; t < 8; ++t){
      int id = tid + t * 256; int row = id >> 4; int k4 = (id & 15) * 4;
      float4 v = *(const float4*)&Kb[(size_t)row * DK + kc + k4];
      Bs[k4+0][row] = v.x; Bs[k4+1][row] = v.y; Bs[k4+2][row] = v.z; Bs[k4+3][row] = v.w;
    }
    __syncthreads();
    int r = tid >> 5, cg = tid & 31;
    #pragma unroll 8
    for (int kx = 0; kx < KC; ++kx){
      float4 a  = *(const float4*)&As[kx][r * 4];
      float4 bv = *(const float4*)&Bs[kx][cg * 4];
      float af[4] = {a.x, a.y, a.z, a.w};
      float bf[4] = {bv.x, bv.y, bv.z, bv.w};
      #pragma unroll
      for (int ri = 0; ri < 4; ++ri)
        #pragma unroll
        for (int ci = 0; ci < 4; ++ci)
          acc[ri][ci] = fmaf(af[ri], bf[ci], acc[ri][ci]);
    }
  }
  int r = tid >> 5, cg = tid & 31;
  int ql = qlen[b], kl = klen[b];
  #pragma unroll
  for (int ri = 0; ri < 4; ++ri){
    int row = r0 + r * 4 + ri;
    float qv = qq[b * TT + row];
    float qr = qR[b * TT + row];
    bool rm = row < ql;
    #pragma unroll
    for (int ci = 0; ci < 4; ++ci){
      int col = cg * 4 + ci;
      float kv = kk[b * TT + col];
      float sq = qv + kv - 2.f * acc[ri][ci];
      float d = sqrtf(fmaxf(sq, 1e-12f));
      bool m = rm && (col < kl);
      float dm = m ? d : 0.f;
      float pm = m ? fabsf(qr - kR[b * TT + col]) : 0.f;
      size_t o = ((size_t)b * TT + row) * TT + col;
      Dout[o] = dm;
      inb[((size_t)b * 2 + 0) * (TT*TT) + row * TT + col] = f2bf(dm);
      inb[((size_t)b * 2 + 1) * (TT*TT) + row * TT + col] = f2bf(pm);
    }
  }
}

// ---------------- conv1: 2ch -> 30ch 5x5, output [b][y][x][c32] ----------------
// block: 32x x 8y tile; thread: 4 px (contig x) x 8 oc; 256 threads
__global__ __launch_bounds__(256) void conv1_k(const u16* __restrict__ inb,
    const u16* __restrict__ w1p, const float* __restrict__ bias, u16* __restrict__ act1){
  __shared__ u16 ilds[2][12][40];
  __shared__ u16 wl[2][25][32];
  __shared__ float bl[32];
  int tile = blockIdx.x, bb = blockIdx.y;
  int x0 = (tile & 3) * 32, y0 = (tile >> 2) * 8;
  int tid = threadIdx.x;
  for (int i = tid; i < 2*12*36; i += 256){
    int c = i / 432; int r2 = i - c*432; int ly = r2 / 36; int lx = r2 - ly*36;
    int gy = y0 - 2 + ly, gx = x0 - 2 + lx;
    u16 v = 0;
    if ((unsigned)gy < 128u && (unsigned)gx < 128u)
      v = inb[((size_t)(bb*2 + c) << 14) + (gy << 7) + gx];
    ilds[c][ly][lx] = v;
  }
  for (int i = tid; i < 1600; i += 256) ((u16*)wl)[i] = w1p[i];
  if (tid < 32) bl[tid] = (tid < MC) ? bias[tid] : 0.f;
  __syncthreads();
  int ocg = tid & 3, x8 = (tid >> 2) & 7, ty = tid >> 5;
  float bv[8];
  #pragma unroll
  for (int o = 0; o < 8; ++o) bv[o] = bl[ocg*8 + o];
  float acc[4][8];
  #pragma unroll
  for (int k = 0; k < 4; ++k)
    #pragma unroll
    for (int o = 0; o < 8; ++o) acc[k][o] = bv[o];
  #pragma unroll
  for (int c = 0; c < 2; ++c){
    #pragma unroll
    for (int dy = 0; dy < 5; ++dy){
      int ly = ty + dy;
      const u16* ip = &ilds[c][ly][4*x8];
      uint2 u0 = *(const uint2*)ip;
      uint2 u1 = *(const uint2*)(ip + 4);
      float xv[8];
      unpack2(u0.x, xv[0], xv[1]); unpack2(u0.y, xv[2], xv[3]);
      unpack2(u1.x, xv[4], xv[5]); unpack2(u1.y, xv[6], xv[7]);
      #pragma unroll
      for (int dx = 0; dx < 5; ++dx){
        uint4 wv = *(const uint4*)&wl[c][dy*5+dx][ocg*8];
        float wf[8];
        unpack2(wv.x, wf[0], wf[1]); unpack2(wv.y, wf[2], wf[3]);
        unpack2(wv.z, wf[4], wf[5]); unpack2(wv.w, wf[6], wf[7]);
        #pragma unroll
        for (int k = 0; k < 4; ++k)
          #pragma unroll
          for (int o = 0; o < 8; ++o)
            acc[k][o] = fmaf(xv[k+dx], wf[o], acc[k][o]);
      }
    }
  }
  int y = y0 + ty;
  #pragma unroll
  for (int k = 0; k < 4; ++k){
    int x = x0 + 4*x8 + k;
    u32 pk[4];
    #pragma unroll
    for (int t = 0; t < 4; ++t)
      pk[t] = pack2bf(fmaxf(acc[k][2*t], 0.f), fmaxf(acc[k][2*t+1], 0.f));
    *(uint4*)(act1 + ((((size_t)bb*128 + y)*128 + x)*32 + ocg*8)) = *(const uint4*)pk;
  }
}

// ---------------- conv2: 30->30 5x5 via MFMA, [b][y][x][c32] in/out ----------------
#define ILDS_ROWB 8448           // 132 * 64 bytes
#define ILDS_BYTES (12*ILDS_ROWB)
#define WLDS_OFF ILDS_BYTES      // 101376
#define SMEM2_BYTES (WLDS_OFF + 25*2048)   // 152576

__global__ __launch_bounds__(512, 1) void conv2_mfma_k(
    const u16* __restrict__ act1, const u16* __restrict__ w2p,
    const float* __restrict__ bias, u16* __restrict__ act2){
  __shared__ __align__(16) char smem[SMEM2_BYTES];
  int yg = blockIdx.x;          // 0..15
  int bb = blockIdx.y;
  int y0 = yg * 8;
  int tid = threadIdx.x;
  // stage pre-swizzled weights linearly: 51200 B
  {
    const uint4* src = (const uint4*)w2p;
    uint4* dst = (uint4*)(smem + WLDS_OFF);
    for (int i = tid; i < 3200; i += 512) dst[i] = src[i];
  }
  // stage input rows y0-2 .. y0+9 into swizzled [row][x132][ic32]
  for (int i = tid; i < 6336; i += 512){
    int r = i / 528; int t2 = i - r*528; int lx = t2 >> 2; int cg = t2 & 3;
    int gy = y0 - 2 + r, gx = lx - 2;
    uint4 v = make_uint4(0,0,0,0);
    if ((unsigned)gy < 128u && (unsigned)gx < 128u)
      v = *(const uint4*)(act1 + ((((size_t)bb*128 + gy)*128 + gx)*32 + cg*8));
    int addr = r*ILDS_ROWB + (((lx<<6) + (cg<<4)) ^ ((lx&7)<<4));
    *(uint4*)(smem + addr) = v;
  }
  __syncthreads();
  int lane = tid & 63, w = tid >> 6;
  int hi = lane >> 5, l31 = lane & 31;
  // precomputed fragment addresses (kh=0; kh=1 via ^32)
  int vB[4][5];
  #pragma unroll
  for (int t = 0; t < 4; ++t)
    #pragma unroll
    for (int dx = 0; dx < 5; ++dx){
      int lx = t*32 + l31 + dx;
      vB[t][dx] = w*ILDS_ROWB + (((lx<<6) + (hi<<4)) ^ ((lx&7)<<4));
    }
  int vA = WLDS_OFF + (((l31<<6) + (hi<<4)) ^ ((l31&7)<<4));
  f32x16 acc[4];
  #pragma unroll
  for (int t = 0; t < 4; ++t)
    #pragma unroll
    for (int r = 0; r < 16; ++r) acc[t][r] = 0.f;
  #pragma unroll
  for (int dy = 0; dy < 5; ++dy){
    #pragma unroll
    for (int dx = 0; dx < 5; ++dx){
      const int tap = dy*5 + dx;
      bf16x8 a0 = *(const bf16x8*)(smem + (vA      ) + tap*2048);
      bf16x8 a1 = *(const bf16x8*)(smem + (vA ^ 32 ) + tap*2048);
      #pragma unroll
      for (int t = 0; t < 4; ++t){
        bf16x8 b0 = *(const bf16x8*)(smem + (vB[t][dx]     ) + dy*ILDS_ROWB);
        acc[t] = __builtin_amdgcn_mfma_f32_32x32x16_bf16(a0, b0, acc[t], 0, 0, 0);
        bf16x8 b1 = *(const bf16x8*)(smem + (vB[t][dx] ^ 32) + dy*ILDS_ROWB);
        acc[t] = __builtin_amdgcn_mfma_f32_32x32x16_bf16(a1, b1, acc[t], 0, 0, 0);
      }
    }
  }
  // bias (C/D row mapping: oc = (reg&3) + 8*(reg>>2) + 4*hi)
  float biasv[16];
  #pragma unroll
  for (int r = 0; r < 16; ++r){
    int oc = (r & 3) + 8*(r >> 2) + 4*hi;
    biasv[r] = (oc < MC) ? bias[oc] : 0.f;
  }
  __syncthreads();   // all taps done before overwriting input region
  // transpose via LDS (per-wave 8KB region inside dead input area)
  int wbase = w * 8192;
  #pragma unroll
  for (int t = 0; t < 4; ++t){
    int px = t*32 + l31;
    #pragma unroll
    for (int q = 0; q < 4; ++q){
      float v0 = fmaxf(acc[t][4*q+0] + biasv[4*q+0], 0.f);
      float v1 = fmaxf(acc[t][4*q+1] + biasv[4*q+1], 0.f);
      float v2 = fmaxf(acc[t][4*q+2] + biasv[4*q+2], 0.f);
      float v3 = fmaxf(acc[t][4*q+3] + biasv[4*q+3], 0.f);
      uint2 p; p.x = pack2bf(v0, v1); p.y = pack2bf(v2, v3);
      int addr = wbase + ((((px<<6) + (q<<4) + (hi<<3))) ^ ((px&7)<<4));
      *(uint2*)(smem + addr) = p;
    }
  }
  int y = y0 + w;
  #pragma unroll
  for (int p = 0; p < 8; ++p){
    int x = p*16 + (lane >> 2), cg = lane & 3;
    int addr = wbase + (((x<<6) + (cg<<4)) ^ ((x&7)<<4));
    uint4 v = *(const uint4*)(smem + addr);
    *(uint4*)(act2 + ((((size_t)bb*128 + y)*128 + x)*32 + cg*8)) = v;
  }
}

// ---------------- conv3 + mask + row softmax + A write + row D*A ----------------
__global__ __launch_bounds__(128) void conv3sm_k(const u16* __restrict__ act2,
    const float* __restrict__ w3, const float* __restrict__ b3, const float* __restrict__ Dbuf,
    const int* __restrict__ qlen, const int* __restrict__ klen,
    float* __restrict__ Aout, float* __restrict__ rowsum, int b0){
  __shared__ __align__(16) char smem3[3*ILDS_ROWB];
  __shared__ float wlds[272];
  __shared__ float redm[2], reds[2], redd[2];
  int bb = blockIdx.x >> 7, i = blockIdx.x & 127, b = b0 + bb;
  int tid = threadIdx.x;
  for (int idx = tid; idx < 1584; idx += 128){
    int r = idx / 528; int t2 = idx - r*528; int lx = t2 >> 2; int cg = t2 & 3;
    int gy = i - 1 + r, gx = lx - 1;
    uint4 v = make_uint4(0,0,0,0);
    if ((unsigned)gy < 128u && (unsigned)gx < 128u)
      v = *(const uint4*)(act2 + ((((size_t)bb*128 + gy)*128 + gx)*32 + cg*8));
    *(uint4*)(smem3 + r*ILDS_ROWB + (((lx<<6) + (cg<<4)) ^ ((lx&7)<<4))) = v;
  }
  for (int idx = tid; idx < 270; idx += 128) wlds[idx] = w3[idx];
  __syncthreads();
  int j = tid;
  float acc = b3[0];
  #pragma unroll
  for (int dy = 0; dy < 3; ++dy){
    #pragma unroll
    for (int dx = 0; dx < 3; ++dx){
      int lx = j + dx;
      u32 u[16];
      #pragma unroll
      for (int cg = 0; cg < 4; ++cg){
        uint4 v = *(const uint4*)(smem3 + dy*ILDS_ROWB + (((lx<<6) + (cg<<4)) ^ ((lx&7)<<4)));
        u[cg*4+0] = v.x; u[cg*4+1] = v.y; u[cg*4+2] = v.z; u[cg*4+3] = v.w;
      }
      #pragma unroll
      for (int c = 0; c < MC; c += 2){
        float lo, hi2; unpack2(u[c>>1], lo, hi2);
        acc = fmaf(lo,  wlds[(c+0)*9 + dy*3 + dx], acc);
        acc = fmaf(hi2, wlds[(c+1)*9 + dy*3 + dx], acc);
      }
    }
  }
  size_t doff = ((size_t)(b * TT + i) << 7) + j;
  float Dv = Dbuf[doff];
  bool m = (i < qlen[b]) && (j < klen[b]);
  float logit = m ? (acc + Dv) : 100.f;
  float xv = -logit;
  float mx = xv;
  #pragma unroll
  for (int o = 32; o; o >>= 1) mx = fmaxf(mx, __shfl_xor(mx, o));
  if ((tid & 63) == 0) redm[tid >> 6] = mx;
  __syncthreads();
  mx = fmaxf(redm[0], redm[1]);
  float e = __expf(xv - mx);
  float s = e;
  #pragma unroll
  for (int o = 32; o; o >>= 1) s += __shfl_xor(s, o);
  if ((tid & 63) == 0) reds[tid >> 6] = s;
  __syncthreads();
  s = reds[0] + reds[1];
  float a = e / s;
  Aout[doff] = a;
  float rd = Dv * a;
  #pragma unroll
  for (int o = 32; o; o >>= 1) rd += __shfl_xor(rd, o);
  if ((tid & 63) == 0) redd[tid >> 6] = rd;
  __syncthreads();
  if (tid == 0) rowsum[b * TT + i] = redd[0] + redd[1];
}

// ---------------- dis reduce ----------------
__global__ __launch_bounds__(128) void dis_k(const float* __restrict__ rowsum, float* __restrict__ out){
  int b = blockIdx.x, tid = threadIdx.x;
  float v = rowsum[b * TT + tid];
  #pragma unroll
  for (int o = 32; o; o >>= 1) v += __shfl_xor(v, o);
  __shared__ float red[2];
  if ((tid & 63) == 0) red[tid >> 6] = v;
  __syncthreads();
  if (tid == 0) out[b] = (red[0] + red[1]) * (1.0f / 128.0f);
}

extern "C" void kernel_launch(void* const* d_in, const int* in_sizes, int n_in,
                              void* d_out, int out_size, void* d_ws, size_t ws_size,
                              hipStream_t stream){
  const float* q_seq = (const float*)d_in[0];
  const int*   q_len = (const int*)d_in[1];
  const float* q_R   = (const float*)d_in[2];
  const float* k_seq = (const float*)d_in[3];
  const int*   k_len = (const int*)d_in[4];
  const float* k_R   = (const float*)d_in[5];
  const float* c1w   = (const float*)d_in[6];
  const float* c1b   = (const float*)d_in[7];
  const float* c2w   = (const float*)d_in[8];
  const float* c2b   = (const float*)d_in[9];
  const float* c3w   = (const float*)d_in[10];
  const float* c3b   = (const float*)d_in[11];
  float* out = (float*)d_out;

  char* base = (char*)d_ws;
  size_t off = 0;
  auto take = [&](size_t bytes)->char*{
    char* p = base + off;
    off = (off + bytes + 255) & ~(size_t)255;
    return p;
  };
  float* Dbuf   = (float*)take((size_t)NB * TT * TT * 4);
  float* qq     = (float*)take((size_t)NB * TT * 4);
  float* kkn    = (float*)take((size_t)NB * TT * 4);
  float* rowsum = (float*)take((size_t)NB * TT * 4);
  u16*   inb    = (u16*)  take((size_t)NB * 2 * TT * TT * 2);
  u16*   w2p    = (u16*)  take(25 * 2048);
  u16*   w1p    = (u16*)  take(1600 * 2);
  size_t fixed = off;
  int BCH = 64;
  while (BCH > 1 && fixed + 2ull * BCH * TT * TT * 32 * 2 + 1024 > ws_size) BCH >>= 1;
  u16* act1 = (u16*)take((size_t)BCH * TT * TT * 32 * 2);
  u16* act2 = (u16*)take((size_t)BCH * TT * TT * 32 * 2);

  prep_w_k<<<26, 256, 0, stream>>>(c2w, c1w, w2p, w1p);
  row_norms_k<<<4096, 256, 0, stream>>>(q_seq, k_seq, qq, kkn);
  cdist_k<<<dim3(4, NB), 256, 0, stream>>>(q_seq, k_seq, qq, kkn, q_len, k_len, q_R, k_R, Dbuf, inb);
  for (int b0 = 0; b0 < NB; b0 += BCH){
    int nb = BCH;
    conv1_k<<<dim3(64, nb), 256, 0, stream>>>(inb + (size_t)b0 * 2 * TT * TT, w1p, c1b, act1);
    conv2_mfma_k<<<dim3(16, nb), 512, 0, stream>>>(act1, w2p, c2b, act2);
    conv3sm_k<<<nb * TT, 128, 0, stream>>>(act2, c3w, c3b, Dbuf, q_len, k_len, out, rowsum, b0);
  }
  dis_k<<<NB, 128, 0, stream>>>(rowsum, out + (size_t)NB * TT * TT);
}

// Round 3
// 240.599 us; speedup vs baseline: 5.8598x; 1.3176x over previous
//
#include <hip/hip_runtime.h>
#include <hip/hip_bf16.h>
#include <stdint.h>

using u16 = unsigned short;
using u32 = unsigned int;

#define NB 64
#define TT 128
#define DK 768
#define MC 30

typedef float f32x16 __attribute__((ext_vector_type(16)));
typedef __bf16 bf16x8 __attribute__((ext_vector_type(8)));

__device__ inline void unpack2(u32 u, float& lo, float& hi){
  union{u32 i; float f;} a, b; a.i = u << 16; b.i = u & 0xFFFF0000u; lo = a.f; hi = b.f;
}
__device__ inline float bf2f(u16 u){ union{u32 i; float f;} v; v.i = ((u32)u) << 16; return v.f; }
__device__ inline u16 f2bf(float f){
  union{u32 i; float f;} v; v.f = f;
  u32 r = v.i + 0x7FFFu + ((v.i >> 16) & 1u);
  return (u16)(r >> 16);
}
__device__ inline u32 pack2bf(float a, float b){ return (u32)f2bf(a) | ((u32)f2bf(b) << 16); }

// ---------------- weight prep: swizzled bf16 layouts ----------------
// w2p byte layout: tap*2048 + ((oc*64 + ic*2) ^ ((oc&7)<<4)), oc,ic in [0,32)
// w1p: [c][tap][oc32] plain bf16
__global__ __launch_bounds__(256) void prep_w_k(const float* __restrict__ w2,
    const float* __restrict__ w1, u16* __restrict__ w2p, u16* __restrict__ w1p){
  int bidx = blockIdx.x;
  if (bidx < 25){
    int tap = bidx;
    for (int i = threadIdx.x; i < 1024; i += 256){
      int oc = i >> 5, ic = i & 31;
      float v = (oc < MC && ic < MC) ? w2[(oc*MC + ic)*25 + tap] : 0.f;
      int byteoff = tap*2048 + (((oc<<6) + (ic<<1)) ^ ((oc&7)<<4));
      *(u16*)((char*)w2p + byteoff) = f2bf(v);
    }
  } else {
    for (int i = threadIdx.x; i < 1600; i += 256){
      int oc = i & 31; int t2 = i >> 5; int tap = t2 % 25; int c = t2 / 25;
      float v = (oc < MC) ? w1[(oc*2 + c)*25 + tap] : 0.f;
      w1p[(c*25 + tap)*32 + oc] = f2bf(v);
    }
  }
}

// ---------------- kernel 1: row sums of squares ----------------
__global__ __launch_bounds__(256) void row_norms_k(const float* __restrict__ q, const float* __restrict__ k,
                                                   float* __restrict__ qq, float* __restrict__ kk){
  int wave = blockIdx.x * 4 + (threadIdx.x >> 6);
  int lane = threadIdx.x & 63;
  const float* src; float* dst; int row;
  if (wave < NB * TT) { src = q; dst = qq; row = wave; }
  else                { src = k; dst = kk; row = wave - NB * TT; }
  const float4* p = (const float4*)(src + (size_t)row * DK + lane * 12);
  float s = 0.f;
  #pragma unroll
  for (int t = 0; t < 3; ++t){ float4 v = p[t]; s += v.x*v.x + v.y*v.y + v.z*v.z + v.w*v.w; }
  #pragma unroll
  for (int o = 32; o; o >>= 1) s += __shfl_xor(s, o);
  if (lane == 0) dst[row] = s;
}

// ---------------- kernel 2: cdist GEMM + P + mask ----------------
#define KC 64
__global__ __launch_bounds__(256) void cdist_k(const float* __restrict__ Q, const float* __restrict__ K,
    const float* __restrict__ qq, const float* __restrict__ kk,
    const int* __restrict__ qlen, const int* __restrict__ klen,
    const float* __restrict__ qR, const float* __restrict__ kR,
    float* __restrict__ Dout, u16* __restrict__ inb){
  __shared__ float As[KC][36];
  __shared__ float Bs[KC][132];
  int b  = blockIdx.y;
  int r0 = blockIdx.x * 32;
  int tid = threadIdx.x;
  const float* Qb = Q + ((size_t)b * TT + r0) * DK;
  const float* Kb = K + (size_t)b * TT * DK;
  float acc[4][4] = {};
  for (int kc = 0; kc < DK; kc += KC){
    __syncthreads();
    #pragma unroll
    for (int t = 0; t < 2; ++t){
      int id = tid + t * 256; int row = id >> 4; int k4 = (id & 15) * 4;
      float4 v = *(const float4*)&Qb[(size_t)row * DK + kc + k4];
      As[k4+0][row] = v.x; As[k4+1][row] = v.y; As[k4+2][row] = v.z; As[k4+3][row] = v.w;
    }
    #pragma unroll
    for (int t = 0; t < 8; ++t){
      int id = tid + t * 256; int row = id >> 4; int k4 = (id & 15) * 4;
      float4 v = *(const float4*)&Kb[(size_t)row * DK + kc + k4];
      Bs[k4+0][row] = v.x; Bs[k4+1][row] = v.y; Bs[k4+2][row] = v.z; Bs[k4+3][row] = v.w;
    }
    __syncthreads();
    int r = tid >> 5, cg = tid & 31;
    #pragma unroll 8
    for (int kx = 0; kx < KC; ++kx){
      float4 a  = *(const float4*)&As[kx][r * 4];
      float4 bv = *(const float4*)&Bs[kx][cg * 4];
      float af[4] = {a.x, a.y, a.z, a.w};
      float bf[4] = {bv.x, bv.y, bv.z, bv.w};
      #pragma unroll
      for (int ri = 0; ri < 4; ++ri)
        #pragma unroll
        for (int ci = 0; ci < 4; ++ci)
          acc[ri][ci] = fmaf(af[ri], bf[ci], acc[ri][ci]);
    }
  }
  int r = tid >> 5, cg = tid & 31;
  int ql = qlen[b], kl = klen[b];
  #pragma unroll
  for (int ri = 0; ri < 4; ++ri){
    int row = r0 + r * 4 + ri;
    float qv = qq[b * TT + row];
    float qr = qR[b * TT + row];
    bool rm = row < ql;
    #pragma unroll
    for (int ci = 0; ci < 4; ++ci){
      int col = cg * 4 + ci;
      float kv = kk[b * TT + col];
      float sq = qv + kv - 2.f * acc[ri][ci];
      float d = sqrtf(fmaxf(sq, 1e-12f));
      bool m = rm && (col < kl);
      float dm = m ? d : 0.f;
      float pm = m ? fabsf(qr - kR[b * TT + col]) : 0.f;
      size_t o = ((size_t)b * TT + row) * TT + col;
      Dout[o] = dm;
      inb[((size_t)b * 2 + 0) * (TT*TT) + row * TT + col] = f2bf(dm);
      inb[((size_t)b * 2 + 1) * (TT*TT) + row * TT + col] = f2bf(pm);
    }
  }
}

// ---------------- conv1: 2ch -> 30ch 5x5, output [b][y][x][c32] ----------------
// block: 32x x 8y tile; thread: 4 px (contig x) x 8 oc; 256 threads
__global__ __launch_bounds__(256) void conv1_k(const u16* __restrict__ inb,
    const u16* __restrict__ w1p, const float* __restrict__ bias, u16* __restrict__ act1){
  __shared__ u16 ilds[2][12][40];
  __shared__ u16 wl[2][25][32];
  __shared__ float bl[32];
  int tile = blockIdx.x, bb = blockIdx.y;
  int x0 = (tile & 3) * 32, y0 = (tile >> 2) * 8;
  int tid = threadIdx.x;
  for (int i = tid; i < 2*12*36; i += 256){
    int c = i / 432; int r2 = i - c*432; int ly = r2 / 36; int lx = r2 - ly*36;
    int gy = y0 - 2 + ly, gx = x0 - 2 + lx;
    u16 v = 0;
    if ((unsigned)gy < 128u && (unsigned)gx < 128u)
      v = inb[((size_t)(bb*2 + c) << 14) + (gy << 7) + gx];
    ilds[c][ly][lx] = v;
  }
  for (int i = tid; i < 1600; i += 256) ((u16*)wl)[i] = w1p[i];
  if (tid < 32) bl[tid] = (tid < MC) ? bias[tid] : 0.f;
  __syncthreads();
  int ocg = tid & 3, x8 = (tid >> 2) & 7, ty = tid >> 5;
  float bv[8];
  #pragma unroll
  for (int o = 0; o < 8; ++o) bv[o] = bl[ocg*8 + o];
  float acc[4][8];
  #pragma unroll
  for (int k = 0; k < 4; ++k)
    #pragma unroll
    for (int o = 0; o < 8; ++o) acc[k][o] = bv[o];
  #pragma unroll
  for (int c = 0; c < 2; ++c){
    #pragma unroll
    for (int dy = 0; dy < 5; ++dy){
      int ly = ty + dy;
      const u16* ip = &ilds[c][ly][4*x8];
      uint2 u0 = *(const uint2*)ip;
      uint2 u1 = *(const uint2*)(ip + 4);
      float xv[8];
      unpack2(u0.x, xv[0], xv[1]); unpack2(u0.y, xv[2], xv[3]);
      unpack2(u1.x, xv[4], xv[5]); unpack2(u1.y, xv[6], xv[7]);
      #pragma unroll
      for (int dx = 0; dx < 5; ++dx){
        uint4 wv = *(const uint4*)&wl[c][dy*5+dx][ocg*8];
        float wf[8];
        unpack2(wv.x, wf[0], wf[1]); unpack2(wv.y, wf[2], wf[3]);
        unpack2(wv.z, wf[4], wf[5]); unpack2(wv.w, wf[6], wf[7]);
        #pragma unroll
        for (int k = 0; k < 4; ++k)
          #pragma unroll
          for (int o = 0; o < 8; ++o)
            acc[k][o] = fmaf(xv[k+dx], wf[o], acc[k][o]);
      }
    }
  }
  int y = y0 + ty;
  #pragma unroll
  for (int k = 0; k < 4; ++k){
    int x = x0 + 4*x8 + k;
    u32 pk[4];
    #pragma unroll
    for (int t = 0; t < 4; ++t)
      pk[t] = pack2bf(fmaxf(acc[k][2*t], 0.f), fmaxf(acc[k][2*t+1], 0.f));
    *(uint4*)(act1 + ((((size_t)bb*128 + y)*128 + x)*32 + ocg*8)) = *(const uint4*)pk;
  }
}

// ---------------- conv2: 30->30 5x5 via MFMA, [b][y][x][c32] in/out ----------------
#define ILDS_ROWB 8448           // 132 * 64 bytes
#define ILDS_BYTES (12*ILDS_ROWB)
#define WLDS_OFF ILDS_BYTES      // 101376
#define SMEM2_BYTES (WLDS_OFF + 25*2048)   // 152576

__global__ __launch_bounds__(512, 1) void conv2_mfma_k(
    const u16* __restrict__ act1, const u16* __restrict__ w2p,
    const float* __restrict__ bias, u16* __restrict__ act2){
  __shared__ __align__(16) char smem[SMEM2_BYTES];
  int yg = blockIdx.x;          // 0..15
  int bb = blockIdx.y;
  int y0 = yg * 8;
  int tid = threadIdx.x;
  // stage pre-swizzled weights linearly: 51200 B
  {
    const uint4* src = (const uint4*)w2p;
    uint4* dst = (uint4*)(smem + WLDS_OFF);
    for (int i = tid; i < 3200; i += 512) dst[i] = src[i];
  }
  // stage input rows y0-2 .. y0+9 into swizzled [row][x132][ic32]
  for (int i = tid; i < 6336; i += 512){
    int r = i / 528; int t2 = i - r*528; int lx = t2 >> 2; int cg = t2 & 3;
    int gy = y0 - 2 + r, gx = lx - 2;
    uint4 v = make_uint4(0,0,0,0);
    if ((unsigned)gy < 128u && (unsigned)gx < 128u)
      v = *(const uint4*)(act1 + ((((size_t)bb*128 + gy)*128 + gx)*32 + cg*8));
    int addr = r*ILDS_ROWB + (((lx<<6) + (cg<<4)) ^ ((lx&7)<<4));
    *(uint4*)(smem + addr) = v;
  }
  __syncthreads();
  int lane = tid & 63, w = tid >> 6;
  int hi = lane >> 5, l31 = lane & 31;
  // precomputed fragment addresses (kh=0; kh=1 via ^32)
  int vB[4][5];
  #pragma unroll
  for (int t = 0; t < 4; ++t)
    #pragma unroll
    for (int dx = 0; dx < 5; ++dx){
      int lx = t*32 + l31 + dx;
      vB[t][dx] = w*ILDS_ROWB + (((lx<<6) + (hi<<4)) ^ ((lx&7)<<4));
    }
  int vA = WLDS_OFF + (((l31<<6) + (hi<<4)) ^ ((l31&7)<<4));
  f32x16 acc[4];
  #pragma unroll
  for (int t = 0; t < 4; ++t)
    #pragma unroll
    for (int r = 0; r < 16; ++r) acc[t][r] = 0.f;
  #pragma unroll
  for (int dy = 0; dy < 5; ++dy){
    #pragma unroll
    for (int dx = 0; dx < 5; ++dx){
      const int tap = dy*5 + dx;
      bf16x8 a0 = *(const bf16x8*)(smem + (vA      ) + tap*2048);
      bf16x8 a1 = *(const bf16x8*)(smem + (vA ^ 32 ) + tap*2048);
      #pragma unroll
      for (int t = 0; t < 4; ++t){
        bf16x8 b0 = *(const bf16x8*)(smem + (vB[t][dx]     ) + dy*ILDS_ROWB);
        acc[t] = __builtin_amdgcn_mfma_f32_32x32x16_bf16(a0, b0, acc[t], 0, 0, 0);
        bf16x8 b1 = *(const bf16x8*)(smem + (vB[t][dx] ^ 32) + dy*ILDS_ROWB);
        acc[t] = __builtin_amdgcn_mfma_f32_32x32x16_bf16(a1, b1, acc[t], 0, 0, 0);
      }
    }
  }
  // bias (C/D row mapping: oc = (reg&3) + 8*(reg>>2) + 4*hi)
  float biasv[16];
  #pragma unroll
  for (int r = 0; r < 16; ++r){
    int oc = (r & 3) + 8*(r >> 2) + 4*hi;
    biasv[r] = (oc < MC) ? bias[oc] : 0.f;
  }
  __syncthreads();   // all taps done before overwriting input region
  // transpose via LDS (per-wave 8KB region inside dead input area)
  int wbase = w * 8192;
  #pragma unroll
  for (int t = 0; t < 4; ++t){
    int px = t*32 + l31;
    #pragma unroll
    for (int q = 0; q < 4; ++q){
      float v0 = fmaxf(acc[t][4*q+0] + biasv[4*q+0], 0.f);
      float v1 = fmaxf(acc[t][4*q+1] + biasv[4*q+1], 0.f);
      float v2 = fmaxf(acc[t][4*q+2] + biasv[4*q+2], 0.f);
      float v3 = fmaxf(acc[t][4*q+3] + biasv[4*q+3], 0.f);
      uint2 p; p.x = pack2bf(v0, v1); p.y = pack2bf(v2, v3);
      int addr = wbase + ((((px<<6) + (q<<4) + (hi<<3))) ^ ((px&7)<<4));
      *(uint2*)(smem + addr) = p;
    }
  }
  int y = y0 + w;
  #pragma unroll
  for (int p = 0; p < 8; ++p){
    int x = p*16 + (lane >> 2), cg = lane & 3;
    int addr = wbase + (((x<<6) + (cg<<4)) ^ ((x&7)<<4));
    uint4 v = *(const uint4*)(smem + addr);
    *(uint4*)(act2 + ((((size_t)bb*128 + y)*128 + x)*32 + cg*8)) = v;
  }
}

// ---------------- conv3 + mask + row softmax + A write + row D*A ----------------
// one block per output row; thread = (px, cg): cg owns 8 channels; no LDS staging
__global__ __launch_bounds__(512) void conv3sm_k(const u16* __restrict__ act2,
    const float* __restrict__ w3, const float* __restrict__ b3, const float* __restrict__ Dbuf,
    const int* __restrict__ qlen, const int* __restrict__ klen,
    float* __restrict__ Aout, float* __restrict__ rowsum, int b0){
  __shared__ float wlds[9][32];
  __shared__ float redm[8], reds[8], redd[8];
  int i  = blockIdx.x;
  int bb = blockIdx.y;
  int b  = b0 + bb;
  int tid = threadIdx.x;
  for (int idx = tid; idx < 288; idx += 512){
    int tap = idx >> 5, c = idx & 31;
    wlds[tap][c] = (c < MC) ? w3[c * 9 + tap] : 0.f;
  }
  __syncthreads();
  int px = tid >> 2, cg = tid & 3, wv = tid >> 6;
  float acc = 0.f;
  #pragma unroll
  for (int dy = 0; dy < 3; ++dy){
    int gy = i - 1 + dy;
    bool rowok = (unsigned)gy < 128u;
    const u16* pr = act2 + ((((size_t)bb * 128 + gy) * 128) + (px - 1)) * 32 + cg * 8;
    #pragma unroll
    for (int dx = 0; dx < 3; ++dx){
      int gx = px - 1 + dx;
      uint4 v = make_uint4(0, 0, 0, 0);
      if (rowok && (unsigned)gx < 128u) v = *(const uint4*)(pr + dx * 32);
      float x[8];
      unpack2(v.x, x[0], x[1]); unpack2(v.y, x[2], x[3]);
      unpack2(v.z, x[4], x[5]); unpack2(v.w, x[6], x[7]);
      const float* wp = &wlds[dy * 3 + dx][cg * 8];
      float4 w0 = *(const float4*)wp;
      float4 w1 = *(const float4*)(wp + 4);
      acc = fmaf(x[0], w0.x, acc); acc = fmaf(x[1], w0.y, acc);
      acc = fmaf(x[2], w0.z, acc); acc = fmaf(x[3], w0.w, acc);
      acc = fmaf(x[4], w1.x, acc); acc = fmaf(x[5], w1.y, acc);
      acc = fmaf(x[6], w1.z, acc); acc = fmaf(x[7], w1.w, acc);
    }
  }
  // channel reduce across the 4 cg lanes (lanes adjacent)
  acc += __shfl_xor(acc, 1);
  acc += __shfl_xor(acc, 2);
  acc += b3[0];
  float Dv = Dbuf[(((size_t)b * 128 + i) << 7) + px];
  bool m = (i < qlen[b]) && (px < klen[b]);
  float xv = m ? -(acc + Dv) : -100.f;
  // row max
  float mx = xv;
  #pragma unroll
  for (int o = 32; o; o >>= 1) mx = fmaxf(mx, __shfl_xor(mx, o));
  if ((tid & 63) == 0) redm[wv] = mx;
  __syncthreads();
  mx = fmaxf(fmaxf(fmaxf(redm[0], redm[1]), fmaxf(redm[2], redm[3])),
             fmaxf(fmaxf(redm[4], redm[5]), fmaxf(redm[6], redm[7])));
  float e = __expf(xv - mx);
  // row sum(e) and sum(D*e) together (each px counted 4x -> ratio unaffected)
  float s  = e;
  float de = Dv * e;
  #pragma unroll
  for (int o = 32; o; o >>= 1){ s += __shfl_xor(s, o); de += __shfl_xor(de, o); }
  if ((tid & 63) == 0){ reds[wv] = s; redd[wv] = de; }
  __syncthreads();
  float s8  = (reds[0] + reds[1]) + (reds[2] + reds[3]) + (reds[4] + reds[5]) + (reds[6] + reds[7]);
  float a = e * 4.0f / s8;
  if (cg == 0) Aout[(((size_t)b * 128 + i) << 7) + px] = a;
  if (tid == 0){
    float d8 = (redd[0] + redd[1]) + (redd[2] + redd[3]) + (redd[4] + redd[5]) + (redd[6] + redd[7]);
    rowsum[b * TT + i] = d8 / s8;   // = sum_px D*a
  }
}

// ---------------- dis reduce ----------------
__global__ __launch_bounds__(128) void dis_k(const float* __restrict__ rowsum, float* __restrict__ out){
  int b = blockIdx.x, tid = threadIdx.x;
  float v = rowsum[b * TT + tid];
  #pragma unroll
  for (int o = 32; o; o >>= 1) v += __shfl_xor(v, o);
  __shared__ float red[2];
  if ((tid & 63) == 0) red[tid >> 6] = v;
  __syncthreads();
  if (tid == 0) out[b] = (red[0] + red[1]) * (1.0f / 128.0f);
}

extern "C" void kernel_launch(void* const* d_in, const int* in_sizes, int n_in,
                              void* d_out, int out_size, void* d_ws, size_t ws_size,
                              hipStream_t stream){
  const float* q_seq = (const float*)d_in[0];
  const int*   q_len = (const int*)d_in[1];
  const float* q_R   = (const float*)d_in[2];
  const float* k_seq = (const float*)d_in[3];
  const int*   k_len = (const int*)d_in[4];
  const float* k_R   = (const float*)d_in[5];
  const float* c1w   = (const float*)d_in[6];
  const float* c1b   = (const float*)d_in[7];
  const float* c2w   = (const float*)d_in[8];
  const float* c2b   = (const float*)d_in[9];
  const float* c3w   = (const float*)d_in[10];
  const float* c3b   = (const float*)d_in[11];
  float* out = (float*)d_out;

  char* base = (char*)d_ws;
  size_t off = 0;
  auto take = [&](size_t bytes)->char*{
    char* p = base + off;
    off = (off + bytes + 255) & ~(size_t)255;
    return p;
  };
  float* Dbuf   = (float*)take((size_t)NB * TT * TT * 4);
  float* qq     = (float*)take((size_t)NB * TT * 4);
  float* kkn    = (float*)take((size_t)NB * TT * 4);
  float* rowsum = (float*)take((size_t)NB * TT * 4);
  u16*   inb    = (u16*)  take((size_t)NB * 2 * TT * TT * 2);
  u16*   w2p    = (u16*)  take(25 * 2048);
  u16*   w1p    = (u16*)  take(1600 * 2);
  size_t fixed = off;
  int BCH = 64;
  while (BCH > 1 && fixed + 2ull * BCH * TT * TT * 32 * 2 + 1024 > ws_size) BCH >>= 1;
  u16* act1 = (u16*)take((size_t)BCH * TT * TT * 32 * 2);
  u16* act2 = (u16*)take((size_t)BCH * TT * TT * 32 * 2);

  prep_w_k<<<26, 256, 0, stream>>>(c2w, c1w, w2p, w1p);
  row_norms_k<<<4096, 256, 0, stream>>>(q_seq, k_seq, qq, kkn);
  cdist_k<<<dim3(4, NB), 256, 0, stream>>>(q_seq, k_seq, qq, kkn, q_len, k_len, q_R, k_R, Dbuf, inb);
  for (int b0 = 0; b0 < NB; b0 += BCH){
    int nb = BCH;
    conv1_k<<<dim3(64, nb), 256, 0, stream>>>(inb + (size_t)b0 * 2 * TT * TT, w1p, c1b, act1);
    conv2_mfma_k<<<dim3(16, nb), 512, 0, stream>>>(act1, w2p, c2b, act2);
    conv3sm_k<<<dim3(TT, nb), 512, 0, stream>>>(act2, c3w, c3b, Dbuf, q_len, k_len, out, rowsum, b0);
  }
  dis_k<<<NB, 128, 0, stream>>>(rowsum, out + (size_t)NB * TT * TT);
}

// Round 5
// 210.458 us; speedup vs baseline: 6.6990x; 1.1432x over previous
//
#include <hip/hip_runtime.h>
#include <hip/hip_bf16.h>
#include <stdint.h>

using u16 = unsigned short;
using u32 = unsigned int;
using u8  = unsigned char;

#define NB 64
#define TT 128
#define DK 768
#define MC 30

typedef float f32x16 __attribute__((ext_vector_type(16)));
typedef long long ll;
typedef __attribute__((ext_vector_type(2))) ll ll2;

__device__ inline void unpack2(u32 u, float& lo, float& hi){
  union{u32 i; float f;} a, b; a.i = u << 16; b.i = u & 0xFFFF0000u; lo = a.f; hi = b.f;
}
__device__ inline u16 f2bf(float f){
  union{u32 i; float f;} v; v.f = f;
  u32 r = v.i + 0x7FFFu + ((v.i >> 16) & 1u);
  return (u16)(r >> 16);
}
__device__ inline u32 pack2bf(float a, float b){ return (u32)f2bf(a) | ((u32)f2bf(b) << 16); }

// ---------------- fp8 e4m3fn pack helpers ----------------
// word-select must be a LITERAL for the builtin -> template on it
#if __has_builtin(__builtin_amdgcn_cvt_pk_fp8_f32)
template<bool HIW>
__device__ inline u32 pk_fp8(float a, float b, u32 old){
  return (u32)__builtin_amdgcn_cvt_pk_fp8_f32(a, b, (int)old, HIW);
}
#else
__device__ inline u8 f2fp8_1(float f){
  union{float f; u32 u;} v; v.f = f;
  u32 s = (v.u >> 24) & 0x80u;
  u32 abs = v.u & 0x7fffffffu;
  if (abs < 0x3c800000u){            // |x| < 2^-6 : subnormal (step 2^-9)
    float sc = fabsf(f) * 512.0f;
    int m = (int)rintf(sc);          // 0..8 (8 == min normal code 0x08)
    return (u8)(s | (u32)m);
  }
  u32 e8 = abs >> 23; u32 mant = abs & 0x7fffffu;
  u32 m3 = mant >> 20; u32 rest = mant & 0xfffffu;
  u32 rb = (rest > 0x80000u) || (rest == 0x80000u && (m3 & 1u));
  m3 += rb;
  u32 E = e8 - 120u;
  if (m3 == 8u){ m3 = 0u; E += 1u; }
  if (E >= 16u || (E == 15u && m3 == 7u)) return (u8)(s | 0x7Eu);  // sat 448
  return (u8)(s | (E << 3) | m3);
}
template<bool HIW>
__device__ inline u32 pk_fp8(float a, float b, u32 old){
  u32 w = (u32)f2fp8_1(a) | ((u32)f2fp8_1(b) << 8);
  return HIW ? ((old & 0x0000FFFFu) | (w << 16)) : ((old & 0xFFFF0000u) | w);
}
#endif

// ---------------- weight prep ----------------
// w2p: fp8 [tap][oc32][ic32] linear, 1024 B per tap
// w1p: bf16 [c][tap][oc32]
__global__ __launch_bounds__(256) void prep_w_k(const float* __restrict__ w2,
    const float* __restrict__ w1, u8* __restrict__ w2p, u16* __restrict__ w1p){
  int bidx = blockIdx.x;
  if (bidx < 25){
    int tap = bidx;
    int i = threadIdx.x;              // one u32 word each: 256 words = 32 oc x 8 q
    int oc = i >> 3, q = i & 7, ic0 = q * 4;
    float v[4];
    #pragma unroll
    for (int j = 0; j < 4; ++j)
      v[j] = (oc < MC && ic0 + j < MC) ? w2[(oc*MC + ic0 + j)*25 + tap] : 0.f;
    u32 w = pk_fp8<false>(v[0], v[1], 0u);
    w = pk_fp8<true>(v[2], v[3], w);
    *(u32*)(w2p + tap*1024 + oc*32 + q*4) = w;
  } else {
    for (int i = threadIdx.x; i < 1600; i += 256){
      int oc = i & 31; int t2 = i >> 5; int tap = t2 % 25; int c = t2 / 25;
      float v = (oc < MC) ? w1[(oc*2 + c)*25 + tap] : 0.f;
      w1p[(c*25 + tap)*32 + oc] = f2bf(v);
    }
  }
}

// ---------------- kernel 1: row sums of squares ----------------
__global__ __launch_bounds__(256) void row_norms_k(const float* __restrict__ q, const float* __restrict__ k,
                                                   float* __restrict__ qq, float* __restrict__ kk){
  int wave = blockIdx.x * 4 + (threadIdx.x >> 6);
  int lane = threadIdx.x & 63;
  const float* src; float* dst; int row;
  if (wave < NB * TT) { src = q; dst = qq; row = wave; }
  else                { src = k; dst = kk; row = wave - NB * TT; }
  const float4* p = (const float4*)(src + (size_t)row * DK + lane * 12);
  float s = 0.f;
  #pragma unroll
  for (int t = 0; t < 3; ++t){ float4 v = p[t]; s += v.x*v.x + v.y*v.y + v.z*v.z + v.w*v.w; }
  #pragma unroll
  for (int o = 32; o; o >>= 1) s += __shfl_xor(s, o);
  if (lane == 0) dst[row] = s;
}

// ---------------- kernel 2: cdist GEMM + P + mask ----------------
#define KC 64
__global__ __launch_bounds__(256) void cdist_k(const float* __restrict__ Q, const float* __restrict__ K,
    const float* __restrict__ qq, const float* __restrict__ kk,
    const int* __restrict__ qlen, const int* __restrict__ klen,
    const float* __restrict__ qR, const float* __restrict__ kR,
    float* __restrict__ Dout, u16* __restrict__ inb){
  __shared__ float As[KC][36];
  __shared__ float Bs[KC][132];
  int b  = blockIdx.y;
  int r0 = blockIdx.x * 32;
  int tid = threadIdx.x;
  const float* Qb = Q + ((size_t)b * TT + r0) * DK;
  const float* Kb = K + (size_t)b * TT * DK;
  float acc[4][4] = {};
  for (int kc = 0; kc < DK; kc += KC){
    __syncthreads();
    #pragma unroll
    for (int t = 0; t < 2; ++t){
      int id = tid + t * 256; int row = id >> 4; int k4 = (id & 15) * 4;
      float4 v = *(const float4*)&Qb[(size_t)row * DK + kc + k4];
      As[k4+0][row] = v.x; As[k4+1][row] = v.y; As[k4+2][row] = v.z; As[k4+3][row] = v.w;
    }
    #pragma unroll
    for (int t = 0; t < 8; ++t){
      int id = tid + t * 256; int row = id >> 4; int k4 = (id & 15) * 4;
      float4 v = *(const float4*)&Kb[(size_t)row * DK + kc + k4];
      Bs[k4+0][row] = v.x; Bs[k4+1][row] = v.y; Bs[k4+2][row] = v.z; Bs[k4+3][row] = v.w;
    }
    __syncthreads();
    int r = tid >> 5, cg = tid & 31;
    #pragma unroll 8
    for (int kx = 0; kx < KC; ++kx){
      float4 a  = *(const float4*)&As[kx][r * 4];
      float4 bv = *(const float4*)&Bs[kx][cg * 4];
      float af[4] = {a.x, a.y, a.z, a.w};
      float bf[4] = {bv.x, bv.y, bv.z, bv.w};
      #pragma unroll
      for (int ri = 0; ri < 4; ++ri)
        #pragma unroll
        for (int ci = 0; ci < 4; ++ci)
          acc[ri][ci] = fmaf(af[ri], bf[ci], acc[ri][ci]);
    }
  }
  int r = tid >> 5, cg = tid & 31;
  int ql = qlen[b], kl = klen[b];
  #pragma unroll
  for (int ri = 0; ri < 4; ++ri){
    int row = r0 + r * 4 + ri;
    float qv = qq[b * TT + row];
    float qr = qR[b * TT + row];
    bool rm = row < ql;
    #pragma unroll
    for (int ci = 0; ci < 4; ++ci){
      int col = cg * 4 + ci;
      float kv = kk[b * TT + col];
      float sq = qv + kv - 2.f * acc[ri][ci];
      float d = sqrtf(fmaxf(sq, 1e-12f));
      bool m = rm && (col < kl);
      float dm = m ? d : 0.f;
      float pm = m ? fabsf(qr - kR[b * TT + col]) : 0.f;
      size_t o = ((size_t)b * TT + row) * TT + col;
      Dout[o] = dm;
      inb[((size_t)b * 2 + 0) * (TT*TT) + row * TT + col] = f2bf(dm);
      inb[((size_t)b * 2 + 1) * (TT*TT) + row * TT + col] = f2bf(pm);
    }
  }
}

// ---------------- conv1: 2ch -> 30ch 5x5, output fp8 [b][y][x][c32] ----------------
__global__ __launch_bounds__(256) void conv1_k(const u16* __restrict__ inb,
    const u16* __restrict__ w1p, const float* __restrict__ bias, u8* __restrict__ act1){
  __shared__ u16 ilds[2][12][40];
  __shared__ u16 wl[2][25][32];
  __shared__ float bl[32];
  int tile = blockIdx.x, bb = blockIdx.y;
  int x0 = (tile & 3) * 32, y0 = (tile >> 2) * 8;
  int tid = threadIdx.x;
  for (int i = tid; i < 2*12*36; i += 256){
    int c = i / 432; int r2 = i - c*432; int ly = r2 / 36; int lx = r2 - ly*36;
    int gy = y0 - 2 + ly, gx = x0 - 2 + lx;
    u16 v = 0;
    if ((unsigned)gy < 128u && (unsigned)gx < 128u)
      v = inb[((size_t)(bb*2 + c) << 14) + (gy << 7) + gx];
    ilds[c][ly][lx] = v;
  }
  for (int i = tid; i < 1600; i += 256) ((u16*)wl)[i] = w1p[i];
  if (tid < 32) bl[tid] = (tid < MC) ? bias[tid] : 0.f;
  __syncthreads();
  int ocg = tid & 3, x8 = (tid >> 2) & 7, ty = tid >> 5;
  float bv[8];
  #pragma unroll
  for (int o = 0; o < 8; ++o) bv[o] = bl[ocg*8 + o];
  float acc[4][8];
  #pragma unroll
  for (int k = 0; k < 4; ++k)
    #pragma unroll
    for (int o = 0; o < 8; ++o) acc[k][o] = bv[o];
  #pragma unroll
  for (int c = 0; c < 2; ++c){
    #pragma unroll
    for (int dy = 0; dy < 5; ++dy){
      int ly = ty + dy;
      const u16* ip = &ilds[c][ly][4*x8];
      uint2 u0 = *(const uint2*)ip;
      uint2 u1 = *(const uint2*)(ip + 4);
      float xv[8];
      unpack2(u0.x, xv[0], xv[1]); unpack2(u0.y, xv[2], xv[3]);
      unpack2(u1.x, xv[4], xv[5]); unpack2(u1.y, xv[6], xv[7]);
      #pragma unroll
      for (int dx = 0; dx < 5; ++dx){
        uint4 wv = *(const uint4*)&wl[c][dy*5+dx][ocg*8];
        float wf[8];
        unpack2(wv.x, wf[0], wf[1]); unpack2(wv.y, wf[2], wf[3]);
        unpack2(wv.z, wf[4], wf[5]); unpack2(wv.w, wf[6], wf[7]);
        #pragma unroll
        for (int k = 0; k < 4; ++k)
          #pragma unroll
          for (int o = 0; o < 8; ++o)
            acc[k][o] = fmaf(xv[k+dx], wf[o], acc[k][o]);
      }
    }
  }
  int y = y0 + ty;
  #pragma unroll
  for (int k = 0; k < 4; ++k){
    int x = x0 + 4*x8 + k;
    float r0 = fmaxf(acc[k][0], 0.f), r1 = fmaxf(acc[k][1], 0.f);
    float r2 = fmaxf(acc[k][2], 0.f), r3 = fmaxf(acc[k][3], 0.f);
    float r4 = fmaxf(acc[k][4], 0.f), r5 = fmaxf(acc[k][5], 0.f);
    float r6 = fmaxf(acc[k][6], 0.f), r7 = fmaxf(acc[k][7], 0.f);
    u32 w0 = pk_fp8<false>(r0, r1, 0u); w0 = pk_fp8<true>(r2, r3, w0);
    u32 w1 = pk_fp8<false>(r4, r5, 0u); w1 = pk_fp8<true>(r6, r7, w1);
    uint2 st; st.x = w0; st.y = w1;
    *(uint2*)(act1 + ((((size_t)(bb*128 + y)*128 + x) << 5) + ocg*8)) = st;
  }
}

// ---------------- conv2: 30->30 5x5 via fp8 MFMA, fp8 in / bf16 out ----------------
#define C2_IN_ROWB 4224                 // 132 px * 32 B
#define C2_IN_BYTES (12*C2_IN_ROWB)     // 50688
#define C2_W_OFF C2_IN_BYTES
#define C2_SMEM (C2_W_OFF + 25*1024)    // 76288

__global__ __launch_bounds__(512, 4) void conv2_mfma_k(
    const u8* __restrict__ act1, const u8* __restrict__ w2p,
    const float* __restrict__ bias, u16* __restrict__ act2){
  __shared__ __align__(16) char smem[C2_SMEM];
  int yg = blockIdx.x;          // 0..15
  int bb = blockIdx.y;
  int y0 = yg * 8;
  int tid = threadIdx.x;
  // stage weights linearly: 25600 B
  {
    const uint4* src = (const uint4*)w2p;
    uint4* dst = (uint4*)(smem + C2_W_OFF);
    for (int i = tid; i < 1600; i += 512) dst[i] = src[i];
  }
  // stage input rows y0-2 .. y0+9 : [r][x132][ic32] fp8, linear (bank-balanced)
  for (int i = tid; i < 3168; i += 512){
    int r = i / 264; int t2 = i - r*264; int lx = t2 >> 1; int h = t2 & 1;
    int gy = y0 - 2 + r, gx = lx - 2;
    uint4 v = make_uint4(0,0,0,0);
    if ((unsigned)gy < 128u && (unsigned)gx < 128u)
      v = *(const uint4*)(act1 + ((((size_t)(bb*128 + gy)*128 + gx)) << 5) + (h << 4));
    *(uint4*)(smem + r*C2_IN_ROWB + (lx << 5) + (h << 4)) = v;
  }
  __syncthreads();
  int lane = tid & 63, w = tid >> 6;
  int hi = lane >> 5, l31 = lane & 31;
  int aBase = C2_W_OFF + (l31 << 5) + (hi << 4);
  int bBase = (l31 << 5) + (hi << 4);
  f32x16 acc[4];
  #pragma unroll
  for (int t = 0; t < 4; ++t)
    #pragma unroll
    for (int r = 0; r < 16; ++r) acc[t][r] = 0.f;
  #pragma unroll
  for (int dy = 0; dy < 5; ++dy){
    const char* rowp = smem + (w + dy)*C2_IN_ROWB + bBase;
    #pragma unroll
    for (int dx = 0; dx < 5; ++dx){
      ll2 a = *(const ll2*)(smem + aBase + (dy*5 + dx)*1024);
      #pragma unroll
      for (int t = 0; t < 4; ++t){
        ll2 b = *(const ll2*)(rowp + (t*32 + dx)*32);
        acc[t] = __builtin_amdgcn_mfma_f32_32x32x16_fp8_fp8(a.x, b.x, acc[t], 0, 0, 0);
        acc[t] = __builtin_amdgcn_mfma_f32_32x32x16_fp8_fp8(a.y, b.y, acc[t], 0, 0, 0);
      }
    }
  }
  // bias (C/D row mapping: oc = (reg&3) + 8*(reg>>2) + 4*hi)
  float biasv[16];
  #pragma unroll
  for (int r = 0; r < 16; ++r){
    int oc = (r & 3) + 8*(r >> 2) + 4*hi;
    biasv[r] = (oc < MC) ? bias[oc] : 0.f;
  }
  __syncthreads();   // all reads done before overwriting LDS
  // transpose via LDS (per-wave 8KB region)
  int wbase = w * 8192;
  #pragma unroll
  for (int t = 0; t < 4; ++t){
    int px = t*32 + l31;
    #pragma unroll
    for (int q = 0; q < 4; ++q){
      float v0 = fmaxf(acc[t][4*q+0] + biasv[4*q+0], 0.f);
      float v1 = fmaxf(acc[t][4*q+1] + biasv[4*q+1], 0.f);
      float v2 = fmaxf(acc[t][4*q+2] + biasv[4*q+2], 0.f);
      float v3 = fmaxf(acc[t][4*q+3] + biasv[4*q+3], 0.f);
      uint2 p; p.x = pack2bf(v0, v1); p.y = pack2bf(v2, v3);
      int addr = wbase + ((((px<<6) + (q<<4) + (hi<<3))) ^ ((px&7)<<4));
      *(uint2*)(smem + addr) = p;
    }
  }
  int y = y0 + w;
  #pragma unroll
  for (int p = 0; p < 8; ++p){
    int x = p*16 + (lane >> 2), cg = lane & 3;
    int addr = wbase + (((x<<6) + (cg<<4)) ^ ((x&7)<<4));
    uint4 v = *(const uint4*)(smem + addr);
    *(uint4*)(act2 + ((((size_t)bb*128 + y)*128 + x)*32 + cg*8)) = v;
  }
}

// ---------------- conv3 + mask + row softmax + A write + row D*A ----------------
__global__ __launch_bounds__(512) void conv3sm_k(const u16* __restrict__ act2,
    const float* __restrict__ w3, const float* __restrict__ b3, const float* __restrict__ Dbuf,
    const int* __restrict__ qlen, const int* __restrict__ klen,
    float* __restrict__ Aout, float* __restrict__ rowsum, int b0){
  __shared__ float wlds[9][32];
  __shared__ float redm[8], reds[8], redd[8];
  int i  = blockIdx.x;
  int bb = blockIdx.y;
  int b  = b0 + bb;
  int tid = threadIdx.x;
  for (int idx = tid; idx < 288; idx += 512){
    int tap = idx >> 5, c = idx & 31;
    wlds[tap][c] = (c < MC) ? w3[c * 9 + tap] : 0.f;
  }
  __syncthreads();
  int px = tid >> 2, cg = tid & 3, wv = tid >> 6;
  float acc = 0.f;
  #pragma unroll
  for (int dy = 0; dy < 3; ++dy){
    int gy = i - 1 + dy;
    bool rowok = (unsigned)gy < 128u;
    const u16* pr = act2 + ((((size_t)bb * 128 + gy) * 128) + (px - 1)) * 32 + cg * 8;
    #pragma unroll
    for (int dx = 0; dx < 3; ++dx){
      int gx = px - 1 + dx;
      uint4 v = make_uint4(0, 0, 0, 0);
      if (rowok && (unsigned)gx < 128u) v = *(const uint4*)(pr + dx * 32);
      float x[8];
      unpack2(v.x, x[0], x[1]); unpack2(v.y, x[2], x[3]);
      unpack2(v.z, x[4], x[5]); unpack2(v.w, x[6], x[7]);
      const float* wp = &wlds[dy * 3 + dx][cg * 8];
      float4 w0 = *(const float4*)wp;
      float4 w1 = *(const float4*)(wp + 4);
      acc = fmaf(x[0], w0.x, acc); acc = fmaf(x[1], w0.y, acc);
      acc = fmaf(x[2], w0.z, acc); acc = fmaf(x[3], w0.w, acc);
      acc = fmaf(x[4], w1.x, acc); acc = fmaf(x[5], w1.y, acc);
      acc = fmaf(x[6], w1.z, acc); acc = fmaf(x[7], w1.w, acc);
    }
  }
  acc += __shfl_xor(acc, 1);
  acc += __shfl_xor(acc, 2);
  acc += b3[0];
  float Dv = Dbuf[(((size_t)b * 128 + i) << 7) + px];
  bool m = (i < qlen[b]) && (px < klen[b]);
  float xv = m ? -(acc + Dv) : -100.f;
  float mx = xv;
  #pragma unroll
  for (int o = 32; o; o >>= 1) mx = fmaxf(mx, __shfl_xor(mx, o));
  if ((tid & 63) == 0) redm[wv] = mx;
  __syncthreads();
  mx = fmaxf(fmaxf(fmaxf(redm[0], redm[1]), fmaxf(redm[2], redm[3])),
             fmaxf(fmaxf(redm[4], redm[5]), fmaxf(redm[6], redm[7])));
  float e = __expf(xv - mx);
  float s  = e;
  float de = Dv * e;
  #pragma unroll
  for (int o = 32; o; o >>= 1){ s += __shfl_xor(s, o); de += __shfl_xor(de, o); }
  if ((tid & 63) == 0){ reds[wv] = s; redd[wv] = de; }
  __syncthreads();
  float s8  = (reds[0] + reds[1]) + (reds[2] + reds[3]) + (reds[4] + reds[5]) + (reds[6] + reds[7]);
  float a = e * 4.0f / s8;
  if (cg == 0) Aout[(((size_t)b * 128 + i) << 7) + px] = a;
  if (tid == 0){
    float d8 = (redd[0] + redd[1]) + (redd[2] + redd[3]) + (redd[4] + redd[5]) + (redd[6] + redd[7]);
    rowsum[b * TT + i] = d8 / s8;
  }
}

// ---------------- dis reduce ----------------
__global__ __launch_bounds__(128) void dis_k(const float* __restrict__ rowsum, float* __restrict__ out){
  int b = blockIdx.x, tid = threadIdx.x;
  float v = rowsum[b * TT + tid];
  #pragma unroll
  for (int o = 32; o; o >>= 1) v += __shfl_xor(v, o);
  __shared__ float red[2];
  if ((tid & 63) == 0) red[tid >> 6] = v;
  __syncthreads();
  if (tid == 0) out[b] = (red[0] + red[1]) * (1.0f / 128.0f);
}

extern "C" void kernel_launch(void* const* d_in, const int* in_sizes, int n_in,
                              void* d_out, int out_size, void* d_ws, size_t ws_size,
                              hipStream_t stream){
  const float* q_seq = (const float*)d_in[0];
  const int*   q_len = (const int*)d_in[1];
  const float* q_R   = (const float*)d_in[2];
  const float* k_seq = (const float*)d_in[3];
  const int*   k_len = (const int*)d_in[4];
  const float* k_R   = (const float*)d_in[5];
  const float* c1w   = (const float*)d_in[6];
  const float* c1b   = (const float*)d_in[7];
  const float* c2w   = (const float*)d_in[8];
  const float* c2b   = (const float*)d_in[9];
  const float* c3w   = (const float*)d_in[10];
  const float* c3b   = (const float*)d_in[11];
  float* out = (float*)d_out;

  char* base = (char*)d_ws;
  size_t off = 0;
  auto take = [&](size_t bytes)->char*{
    char* p = base + off;
    off = (off + bytes + 255) & ~(size_t)255;
    return p;
  };
  float* Dbuf   = (float*)take((size_t)NB * TT * TT * 4);
  float* qq     = (float*)take((size_t)NB * TT * 4);
  float* kkn    = (float*)take((size_t)NB * TT * 4);
  float* rowsum = (float*)take((size_t)NB * TT * 4);
  u16*   inb    = (u16*)  take((size_t)NB * 2 * TT * TT * 2);
  u8*    w2p    = (u8*)   take(25 * 1024);
  u16*   w1p    = (u16*)  take(1600 * 2);
  size_t fixed = off;
  int BCH = 64;
  while (BCH > 1 && fixed + (size_t)BCH * TT * TT * 96 + 1024 > ws_size) BCH >>= 1;
  u8*  act1 = (u8*) take((size_t)BCH * TT * TT * 32);
  u16* act2 = (u16*)take((size_t)BCH * TT * TT * 32 * 2);

  prep_w_k<<<26, 256, 0, stream>>>(c2w, c1w, w2p, w1p);
  row_norms_k<<<4096, 256, 0, stream>>>(q_seq, k_seq, qq, kkn);
  cdist_k<<<dim3(4, NB), 256, 0, stream>>>(q_seq, k_seq, qq, kkn, q_len, k_len, q_R, k_R, Dbuf, inb);
  for (int b0 = 0; b0 < NB; b0 += BCH){
    int nb = BCH;
    conv1_k<<<dim3(64, nb), 256, 0, stream>>>(inb + (size_t)b0 * 2 * TT * TT, w1p, c1b, act1);
    conv2_mfma_k<<<dim3(16, nb), 512, 0, stream>>>(act1, w2p, c2b, act2);
    conv3sm_k<<<dim3(TT, nb), 512, 0, stream>>>(act2, c3w, c3b, Dbuf, q_len, k_len, out, rowsum, b0);
  }
  dis_k<<<NB, 128, 0, stream>>>(rowsum, out + (size_t)NB * TT * TT);
}

// Round 6
// 184.193 us; speedup vs baseline: 7.6543x; 1.1426x over previous
//
#include <hip/hip_runtime.h>
#include <hip/hip_bf16.h>
#include <stdint.h>

using u16 = unsigned short;
using u32 = unsigned int;
using u8  = unsigned char;

#define NB 64
#define TT 128
#define DK 768
#define MC 30

typedef float f32x16 __attribute__((ext_vector_type(16)));
typedef long long ll;
typedef __attribute__((ext_vector_type(2))) ll ll2;

__device__ inline void unpack2(u32 u, float& lo, float& hi){
  union{u32 i; float f;} a, b; a.i = u << 16; b.i = u & 0xFFFF0000u; lo = a.f; hi = b.f;
}
__device__ inline u16 f2bf(float f){
  union{u32 i; float f;} v; v.f = f;
  u32 r = v.i + 0x7FFFu + ((v.i >> 16) & 1u);
  return (u16)(r >> 16);
}
__device__ inline u32 pack2bf(float a, float b){ return (u32)f2bf(a) | ((u32)f2bf(b) << 16); }

// ---------------- fp8 e4m3fn pack/unpack helpers ----------------
#if __has_builtin(__builtin_amdgcn_cvt_pk_fp8_f32)
template<bool HIW>
__device__ inline u32 pk_fp8(float a, float b, u32 old){
  return (u32)__builtin_amdgcn_cvt_pk_fp8_f32(a, b, (int)old, HIW);
}
#else
__device__ inline u8 f2fp8_1(float f){
  union{float f; u32 u;} v; v.f = f;
  u32 s = (v.u >> 24) & 0x80u;
  u32 abs = v.u & 0x7fffffffu;
  if (abs < 0x3c800000u){
    float sc = fabsf(f) * 512.0f;
    int m = (int)rintf(sc);
    return (u8)(s | (u32)m);
  }
  u32 e8 = abs >> 23; u32 mant = abs & 0x7fffffu;
  u32 m3 = mant >> 20; u32 rest = mant & 0xfffffu;
  u32 rb = (rest > 0x80000u) || (rest == 0x80000u && (m3 & 1u));
  m3 += rb;
  u32 E = e8 - 120u;
  if (m3 == 8u){ m3 = 0u; E += 1u; }
  if (E >= 16u || (E == 15u && m3 == 7u)) return (u8)(s | 0x7Eu);
  return (u8)(s | (E << 3) | m3);
}
template<bool HIW>
__device__ inline u32 pk_fp8(float a, float b, u32 old){
  u32 w = (u32)f2fp8_1(a) | ((u32)f2fp8_1(b) << 8);
  return HIW ? ((old & 0x0000FFFFu) | (w << 16)) : ((old & 0xFFFF0000u) | w);
}
#endif

#if __has_builtin(__builtin_amdgcn_cvt_pk_f32_fp8)
// decode 4 fp8 bytes of word w into x[0..3]
__device__ inline void upk_fp8x4(u32 w, float* x){
  auto a0 = __builtin_amdgcn_cvt_pk_f32_fp8((int)w, false);
  auto a1 = __builtin_amdgcn_cvt_pk_f32_fp8((int)w, true);
  x[0] = a0[0]; x[1] = a0[1]; x[2] = a1[0]; x[3] = a1[1];
}
#else
__device__ inline float fp8_1(u32 byte){
  u32 s = (byte & 0x80u) << 24;
  u32 E = (byte >> 3) & 15u, M = byte & 7u;
  union{u32 u; float f;} v;
  if (E == 0){ v.f = (float)M * (1.0f/512.0f); v.u |= s; }
  else v.u = s | ((E + 120u) << 23) | (M << 20);
  return v.f;
}
__device__ inline void upk_fp8x4(u32 w, float* x){
  x[0] = fp8_1(w & 255u); x[1] = fp8_1((w >> 8) & 255u);
  x[2] = fp8_1((w >> 16) & 255u); x[3] = fp8_1(w >> 24);
}
#endif

// ---------------- weight prep ----------------
// w2p: fp8 [tap][oc32][ic32] linear, 1024 B per tap
// w1p: bf16 [c][tap][oc32]
__global__ __launch_bounds__(256) void prep_w_k(const float* __restrict__ w2,
    const float* __restrict__ w1, u8* __restrict__ w2p, u16* __restrict__ w1p){
  int bidx = blockIdx.x;
  if (bidx < 25){
    int tap = bidx;
    int i = threadIdx.x;
    int oc = i >> 3, q = i & 7, ic0 = q * 4;
    float v[4];
    #pragma unroll
    for (int j = 0; j < 4; ++j)
      v[j] = (oc < MC && ic0 + j < MC) ? w2[(oc*MC + ic0 + j)*25 + tap] : 0.f;
    u32 w = pk_fp8<false>(v[0], v[1], 0u);
    w = pk_fp8<true>(v[2], v[3], w);
    *(u32*)(w2p + tap*1024 + oc*32 + q*4) = w;
  } else {
    for (int i = threadIdx.x; i < 1600; i += 256){
      int oc = i & 31; int t2 = i >> 5; int tap = t2 % 25; int c = t2 / 25;
      float v = (oc < MC) ? w1[(oc*2 + c)*25 + tap] : 0.f;
      w1p[(c*25 + tap)*32 + oc] = f2bf(v);
    }
  }
}

// ---------------- kernel 1: row sums of squares ----------------
__global__ __launch_bounds__(256) void row_norms_k(const float* __restrict__ q, const float* __restrict__ k,
                                                   float* __restrict__ qq, float* __restrict__ kk){
  int wave = blockIdx.x * 4 + (threadIdx.x >> 6);
  int lane = threadIdx.x & 63;
  const float* src; float* dst; int row;
  if (wave < NB * TT) { src = q; dst = qq; row = wave; }
  else                { src = k; dst = kk; row = wave - NB * TT; }
  const float4* p = (const float4*)(src + (size_t)row * DK + lane * 12);
  float s = 0.f;
  #pragma unroll
  for (int t = 0; t < 3; ++t){ float4 v = p[t]; s += v.x*v.x + v.y*v.y + v.z*v.z + v.w*v.w; }
  #pragma unroll
  for (int o = 32; o; o >>= 1) s += __shfl_xor(s, o);
  if (lane == 0) dst[row] = s;
}

// ---------------- kernel 2: cdist GEMM + P + mask ----------------
#define KC 64
__global__ __launch_bounds__(256) void cdist_k(const float* __restrict__ Q, const float* __restrict__ K,
    const float* __restrict__ qq, const float* __restrict__ kk,
    const int* __restrict__ qlen, const int* __restrict__ klen,
    const float* __restrict__ qR, const float* __restrict__ kR,
    float* __restrict__ Dout, u16* __restrict__ inb){
  __shared__ float As[KC][36];
  __shared__ float Bs[KC][132];
  int b  = blockIdx.y;
  int r0 = blockIdx.x * 32;
  int tid = threadIdx.x;
  const float* Qb = Q + ((size_t)b * TT + r0) * DK;
  const float* Kb = K + (size_t)b * TT * DK;
  float acc[4][4] = {};
  for (int kc = 0; kc < DK; kc += KC){
    __syncthreads();
    #pragma unroll
    for (int t = 0; t < 2; ++t){
      int id = tid + t * 256; int row = id >> 4; int k4 = (id & 15) * 4;
      float4 v = *(const float4*)&Qb[(size_t)row * DK + kc + k4];
      As[k4+0][row] = v.x; As[k4+1][row] = v.y; As[k4+2][row] = v.z; As[k4+3][row] = v.w;
    }
    #pragma unroll
    for (int t = 0; t < 8; ++t){
      int id = tid + t * 256; int row = id >> 4; int k4 = (id & 15) * 4;
      float4 v = *(const float4*)&Kb[(size_t)row * DK + kc + k4];
      Bs[k4+0][row] = v.x; Bs[k4+1][row] = v.y; Bs[k4+2][row] = v.z; Bs[k4+3][row] = v.w;
    }
    __syncthreads();
    int r = tid >> 5, cg = tid & 31;
    #pragma unroll 8
    for (int kx = 0; kx < KC; ++kx){
      float4 a  = *(const float4*)&As[kx][r * 4];
      float4 bv = *(const float4*)&Bs[kx][cg * 4];
      float af[4] = {a.x, a.y, a.z, a.w};
      float bf[4] = {bv.x, bv.y, bv.z, bv.w};
      #pragma unroll
      for (int ri = 0; ri < 4; ++ri)
        #pragma unroll
        for (int ci = 0; ci < 4; ++ci)
          acc[ri][ci] = fmaf(af[ri], bf[ci], acc[ri][ci]);
    }
  }
  int r = tid >> 5, cg = tid & 31;
  int ql = qlen[b], kl = klen[b];
  #pragma unroll
  for (int ri = 0; ri < 4; ++ri){
    int row = r0 + r * 4 + ri;
    float qv = qq[b * TT + row];
    float qr = qR[b * TT + row];
    bool rm = row < ql;
    #pragma unroll
    for (int ci = 0; ci < 4; ++ci){
      int col = cg * 4 + ci;
      float kv = kk[b * TT + col];
      float sq = qv + kv - 2.f * acc[ri][ci];
      float d = sqrtf(fmaxf(sq, 1e-12f));
      bool m = rm && (col < kl);
      float dm = m ? d : 0.f;
      float pm = m ? fabsf(qr - kR[b * TT + col]) : 0.f;
      size_t o = ((size_t)b * TT + row) * TT + col;
      Dout[o] = dm;
      inb[((size_t)b * 2 + 0) * (TT*TT) + row * TT + col] = f2bf(dm);
      inb[((size_t)b * 2 + 1) * (TT*TT) + row * TT + col] = f2bf(pm);
    }
  }
}

// ---------------- conv1: 2ch -> 30ch 5x5, output fp8 [b][y][x][c32] ----------------
__global__ __launch_bounds__(256) void conv1_k(const u16* __restrict__ inb,
    const u16* __restrict__ w1p, const float* __restrict__ bias, u8* __restrict__ act1){
  __shared__ u16 ilds[2][12][40];
  __shared__ u16 wl[2][25][32];
  __shared__ float bl[32];
  int tile = blockIdx.x, bb = blockIdx.y;
  int x0 = (tile & 3) * 32, y0 = (tile >> 2) * 8;
  int tid = threadIdx.x;
  for (int i = tid; i < 2*12*36; i += 256){
    int c = i / 432; int r2 = i - c*432; int ly = r2 / 36; int lx = r2 - ly*36;
    int gy = y0 - 2 + ly, gx = x0 - 2 + lx;
    u16 v = 0;
    if ((unsigned)gy < 128u && (unsigned)gx < 128u)
      v = inb[((size_t)(bb*2 + c) << 14) + (gy << 7) + gx];
    ilds[c][ly][lx] = v;
  }
  for (int i = tid; i < 1600; i += 256) ((u16*)wl)[i] = w1p[i];
  if (tid < 32) bl[tid] = (tid < MC) ? bias[tid] : 0.f;
  __syncthreads();
  int ocg = tid & 3, x8 = (tid >> 2) & 7, ty = tid >> 5;
  float bv[8];
  #pragma unroll
  for (int o = 0; o < 8; ++o) bv[o] = bl[ocg*8 + o];
  float acc[4][8];
  #pragma unroll
  for (int k = 0; k < 4; ++k)
    #pragma unroll
    for (int o = 0; o < 8; ++o) acc[k][o] = bv[o];
  #pragma unroll
  for (int c = 0; c < 2; ++c){
    #pragma unroll
    for (int dy = 0; dy < 5; ++dy){
      int ly = ty + dy;
      const u16* ip = &ilds[c][ly][4*x8];
      uint2 u0 = *(const uint2*)ip;
      uint2 u1 = *(const uint2*)(ip + 4);
      float xv[8];
      unpack2(u0.x, xv[0], xv[1]); unpack2(u0.y, xv[2], xv[3]);
      unpack2(u1.x, xv[4], xv[5]); unpack2(u1.y, xv[6], xv[7]);
      #pragma unroll
      for (int dx = 0; dx < 5; ++dx){
        uint4 wv = *(const uint4*)&wl[c][dy*5+dx][ocg*8];
        float wf[8];
        unpack2(wv.x, wf[0], wf[1]); unpack2(wv.y, wf[2], wf[3]);
        unpack2(wv.z, wf[4], wf[5]); unpack2(wv.w, wf[6], wf[7]);
        #pragma unroll
        for (int k = 0; k < 4; ++k)
          #pragma unroll
          for (int o = 0; o < 8; ++o)
            acc[k][o] = fmaf(xv[k+dx], wf[o], acc[k][o]);
      }
    }
  }
  int y = y0 + ty;
  #pragma unroll
  for (int k = 0; k < 4; ++k){
    int x = x0 + 4*x8 + k;
    float r0 = fmaxf(acc[k][0], 0.f), r1 = fmaxf(acc[k][1], 0.f);
    float r2 = fmaxf(acc[k][2], 0.f), r3 = fmaxf(acc[k][3], 0.f);
    float r4 = fmaxf(acc[k][4], 0.f), r5 = fmaxf(acc[k][5], 0.f);
    float r6 = fmaxf(acc[k][6], 0.f), r7 = fmaxf(acc[k][7], 0.f);
    u32 w0 = pk_fp8<false>(r0, r1, 0u); w0 = pk_fp8<true>(r2, r3, w0);
    u32 w1 = pk_fp8<false>(r4, r5, 0u); w1 = pk_fp8<true>(r6, r7, w1);
    uint2 st; st.x = w0; st.y = w1;
    *(uint2*)(act1 + ((((size_t)(bb*128 + y)*128 + x) << 5) + ocg*8)) = st;
  }
}

// ---------------- conv2: 30->30 5x5 via fp8 MFMA, fp8 in / fp8 out ----------------
#define C2_IN_ROWB 4224                 // 132 px * 32 B
#define C2_IN_BYTES (12*C2_IN_ROWB)     // 50688
#define C2_W_OFF C2_IN_BYTES
#define C2_SMEM (C2_W_OFF + 25*1024)    // 76288

__global__ __launch_bounds__(512, 4) void conv2_mfma_k(
    const u8* __restrict__ act1, const u8* __restrict__ w2p,
    const float* __restrict__ bias, u8* __restrict__ act2){
  __shared__ __align__(16) char smem[C2_SMEM];
  int yg = blockIdx.x;          // 0..15
  int bb = blockIdx.y;
  int y0 = yg * 8;
  int tid = threadIdx.x;
  // stage weights linearly: 25600 B
  {
    const uint4* src = (const uint4*)w2p;
    uint4* dst = (uint4*)(smem + C2_W_OFF);
    for (int i = tid; i < 1600; i += 512) dst[i] = src[i];
  }
  // stage input rows y0-2 .. y0+9 : [r][x132][ic32] fp8, linear (bank-balanced)
  for (int i = tid; i < 3168; i += 512){
    int r = i / 264; int t2 = i - r*264; int lx = t2 >> 1; int h = t2 & 1;
    int gy = y0 - 2 + r, gx = lx - 2;
    uint4 v = make_uint4(0,0,0,0);
    if ((unsigned)gy < 128u && (unsigned)gx < 128u)
      v = *(const uint4*)(act1 + ((((size_t)(bb*128 + gy)*128 + gx)) << 5) + (h << 4));
    *(uint4*)(smem + r*C2_IN_ROWB + (lx << 5) + (h << 4)) = v;
  }
  __syncthreads();
  int lane = tid & 63, w = tid >> 6;
  int hi = lane >> 5, l31 = lane & 31;
  int aBase = C2_W_OFF + (l31 << 5) + (hi << 4);
  int bBase = (l31 << 5) + (hi << 4);
  f32x16 acc[4];
  #pragma unroll
  for (int t = 0; t < 4; ++t)
    #pragma unroll
    for (int r = 0; r < 16; ++r) acc[t][r] = 0.f;
  #pragma unroll
  for (int dy = 0; dy < 5; ++dy){
    const char* rowp = smem + (w + dy)*C2_IN_ROWB + bBase;
    #pragma unroll
    for (int dx = 0; dx < 5; ++dx){
      ll2 a = *(const ll2*)(smem + aBase + (dy*5 + dx)*1024);
      #pragma unroll
      for (int t = 0; t < 4; ++t){
        ll2 b = *(const ll2*)(rowp + (t*32 + dx)*32);
        acc[t] = __builtin_amdgcn_mfma_f32_32x32x16_fp8_fp8(a.x, b.x, acc[t], 0, 0, 0);
        acc[t] = __builtin_amdgcn_mfma_f32_32x32x16_fp8_fp8(a.y, b.y, acc[t], 0, 0, 0);
      }
    }
  }
  // bias (C/D row mapping: oc = (reg&3) + 8*(reg>>2) + 4*hi)
  float biasv[16];
  #pragma unroll
  for (int r = 0; r < 16; ++r){
    int oc = (r & 3) + 8*(r >> 2) + 4*hi;
    biasv[r] = (oc < MC) ? bias[oc] : 0.f;
  }
  __syncthreads();   // all reads done before overwriting LDS
  // transpose via LDS (per-wave 4KB region, fp8)
  int wbase = w * 8192;
  #pragma unroll
  for (int t = 0; t < 4; ++t){
    int px = t*32 + l31;
    #pragma unroll
    for (int q = 0; q < 4; ++q){
      float v0 = fmaxf(acc[t][4*q+0] + biasv[4*q+0], 0.f);
      float v1 = fmaxf(acc[t][4*q+1] + biasv[4*q+1], 0.f);
      float v2 = fmaxf(acc[t][4*q+2] + biasv[4*q+2], 0.f);
      float v3 = fmaxf(acc[t][4*q+3] + biasv[4*q+3], 0.f);
      u32 word = pk_fp8<false>(v0, v1, 0u);
      word = pk_fp8<true>(v2, v3, word);
      int addr = wbase + (((px<<5) + (q<<3) + (hi<<2)) ^ ((px&7)<<3));
      *(u32*)(smem + addr) = word;
    }
  }
  int y = y0 + w;
  #pragma unroll
  for (int p = 0; p < 8; ++p){
    int x = p*16 + (lane >> 2), cg = lane & 3;
    int addr = wbase + (((x<<5) + (cg<<3)) ^ ((x&7)<<3));
    uint2 v = *(const uint2*)(smem + addr);
    *(uint2*)(act2 + ((((size_t)bb*128 + y)*128 + x) << 5) + cg*8) = v;
  }
}

// ---------------- conv3 + mask + row softmax + A write + row D*A ----------------
// one block per output row; thread = (px, cg); factorized x-pass via LDS exchange
__global__ __launch_bounds__(512) void conv3sm_k(const u8* __restrict__ act2,
    const float* __restrict__ w3, const float* __restrict__ b3, const float* __restrict__ Dbuf,
    const int* __restrict__ qlen, const int* __restrict__ klen,
    float* __restrict__ Aout, float* __restrict__ rowsum, int b0){
  __shared__ float wlds[9][32];
  __shared__ float ex0[512], ex2[512];
  __shared__ float redm[8], reds[8], redd[8];
  int i  = blockIdx.x;
  int bb = blockIdx.y;
  int b  = b0 + bb;
  int tid = threadIdx.x;
  for (int idx = tid; idx < 288; idx += 512){
    int tap = idx >> 5, c = idx & 31;
    wlds[tap][c] = (c < MC) ? w3[c * 9 + tap] : 0.f;
  }
  __syncthreads();
  int px = tid >> 2, cg = tid & 3, wv = tid >> 6;
  // per-dx channel-partials over own pixel, summed across the 3 rows
  float T0 = 0.f, T1 = 0.f, T2 = 0.f;
  #pragma unroll
  for (int dy = 0; dy < 3; ++dy){
    int gy = i - 1 + dy;
    uint2 v = make_uint2(0, 0);
    if ((unsigned)gy < 128u)
      v = *(const uint2*)(act2 + ((((size_t)bb*128 + gy)*128 + px) << 5) + cg*8);
    float x[8];
    upk_fp8x4(v.x, x);
    upk_fp8x4(v.y, x + 4);
    const float* w0p = &wlds[dy*3 + 0][cg*8];
    const float* w1p = &wlds[dy*3 + 1][cg*8];
    const float* w2q = &wlds[dy*3 + 2][cg*8];
    #pragma unroll
    for (int c = 0; c < 8; ++c){
      T0 = fmaf(x[c], w0p[c], T0);
      T1 = fmaf(x[c], w1p[c], T1);
      T2 = fmaf(x[c], w2q[c], T2);
    }
  }
  ex0[tid] = T0; ex2[tid] = T2;
  __syncthreads();
  float acc = T1;
  if (px > 0)   acc += ex0[tid - 4];   // dx=0 taps come from source px-1
  if (px < 127) acc += ex2[tid + 4];   // dx=2 taps come from source px+1
  acc += __shfl_xor(acc, 1);
  acc += __shfl_xor(acc, 2);
  acc += b3[0];
  float Dv = Dbuf[(((size_t)b * 128 + i) << 7) + px];
  bool m = (i < qlen[b]) && (px < klen[b]);
  float xv = m ? -(acc + Dv) : -100.f;
  float mx = xv;
  #pragma unroll
  for (int o = 32; o; o >>= 1) mx = fmaxf(mx, __shfl_xor(mx, o));
  if ((tid & 63) == 0) redm[wv] = mx;
  __syncthreads();
  mx = fmaxf(fmaxf(fmaxf(redm[0], redm[1]), fmaxf(redm[2], redm[3])),
             fmaxf(fmaxf(redm[4], redm[5]), fmaxf(redm[6], redm[7])));
  float e = __expf(xv - mx);
  float s  = e;
  float de = Dv * e;
  #pragma unroll
  for (int o = 32; o; o >>= 1){ s += __shfl_xor(s, o); de += __shfl_xor(de, o); }
  if ((tid & 63) == 0){ reds[wv] = s; redd[wv] = de; }
  __syncthreads();
  float s8  = (reds[0] + reds[1]) + (reds[2] + reds[3]) + (reds[4] + reds[5]) + (reds[6] + reds[7]);
  float a = e * 4.0f / s8;
  if (cg == 0) Aout[(((size_t)b * 128 + i) << 7) + px] = a;
  if (tid == 0){
    float d8 = (redd[0] + redd[1]) + (redd[2] + redd[3]) + (redd[4] + redd[5]) + (redd[6] + redd[7]);
    rowsum[b * TT + i] = d8 / s8;
  }
}

// ---------------- dis reduce ----------------
__global__ __launch_bounds__(128) void dis_k(const float* __restrict__ rowsum, float* __restrict__ out){
  int b = blockIdx.x, tid = threadIdx.x;
  float v = rowsum[b * TT + tid];
  #pragma unroll
  for (int o = 32; o; o >>= 1) v += __shfl_xor(v, o);
  __shared__ float red[2];
  if ((tid & 63) == 0) red[tid >> 6] = v;
  __syncthreads();
  if (tid == 0) out[b] = (red[0] + red[1]) * (1.0f / 128.0f);
}

extern "C" void kernel_launch(void* const* d_in, const int* in_sizes, int n_in,
                              void* d_out, int out_size, void* d_ws, size_t ws_size,
                              hipStream_t stream){
  const float* q_seq = (const float*)d_in[0];
  const int*   q_len = (const int*)d_in[1];
  const float* q_R   = (const float*)d_in[2];
  const float* k_seq = (const float*)d_in[3];
  const int*   k_len = (const int*)d_in[4];
  const float* k_R   = (const float*)d_in[5];
  const float* c1w   = (const float*)d_in[6];
  const float* c1b   = (const float*)d_in[7];
  const float* c2w   = (const float*)d_in[8];
  const float* c2b   = (const float*)d_in[9];
  const float* c3w   = (const float*)d_in[10];
  const float* c3b   = (const float*)d_in[11];
  float* out = (float*)d_out;

  char* base = (char*)d_ws;
  size_t off = 0;
  auto take = [&](size_t bytes)->char*{
    char* p = base + off;
    off = (off + bytes + 255) & ~(size_t)255;
    return p;
  };
  float* Dbuf   = (float*)take((size_t)NB * TT * TT * 4);
  float* qq     = (float*)take((size_t)NB * TT * 4);
  float* kkn    = (float*)take((size_t)NB * TT * 4);
  float* rowsum = (float*)take((size_t)NB * TT * 4);
  u16*   inb    = (u16*)  take((size_t)NB * 2 * TT * TT * 2);
  u8*    w2p    = (u8*)   take(25 * 1024);
  u16*   w1p    = (u16*)  take(1600 * 2);
  size_t fixed = off;
  int BCH = 64;
  while (BCH > 1 && fixed + (size_t)BCH * TT * TT * 64 + 1024 > ws_size) BCH >>= 1;
  u8* act1 = (u8*)take((size_t)BCH * TT * TT * 32);
  u8* act2 = (u8*)take((size_t)BCH * TT * TT * 32);

  prep_w_k<<<26, 256, 0, stream>>>(c2w, c1w, w2p, w1p);
  row_norms_k<<<4096, 256, 0, stream>>>(q_seq, k_seq, qq, kkn);
  cdist_k<<<dim3(4, NB), 256, 0, stream>>>(q_seq, k_seq, qq, kkn, q_len, k_len, q_R, k_R, Dbuf, inb);
  for (int b0 = 0; b0 < NB; b0 += BCH){
    int nb = BCH;
    conv1_k<<<dim3(64, nb), 256, 0, stream>>>(inb + (size_t)b0 * 2 * TT * TT, w1p, c1b, act1);
    conv2_mfma_k<<<dim3(16, nb), 512, 0, stream>>>(act1, w2p, c2b, act2);
    conv3sm_k<<<dim3(TT, nb), 512, 0, stream>>>(act2, c3w, c3b, Dbuf, q_len, k_len, out, rowsum, b0);
  }
  dis_k<<<NB, 128, 0, stream>>>(rowsum, out + (size_t)NB * TT * TT);
}

// Round 7
// 160.386 us; speedup vs baseline: 8.7905x; 1.1484x over previous
//
#include <hip/hip_runtime.h>
#include <hip/hip_bf16.h>
#include <stdint.h>

using u16 = unsigned short;
using u32 = unsigned int;
using u8  = unsigned char;

#define NB 64
#define TT 128
#define DK 768
#define MC 30

typedef float f32x16 __attribute__((ext_vector_type(16)));
typedef __bf16 bf16x8 __attribute__((ext_vector_type(8)));
typedef long long ll;
typedef __attribute__((ext_vector_type(2))) ll ll2;

__device__ inline void unpack2(u32 u, float& lo, float& hi){
  union{u32 i; float f;} a, b; a.i = u << 16; b.i = u & 0xFFFF0000u; lo = a.f; hi = b.f;
}
__device__ inline u16 f2bf(float f){
  union{u32 i; float f;} v; v.f = f;
  u32 r = v.i + 0x7FFFu + ((v.i >> 16) & 1u);
  return (u16)(r >> 16);
}
__device__ inline u32 pack2bf(float a, float b){ return (u32)f2bf(a) | ((u32)f2bf(b) << 16); }

// ---------------- fp8 e4m3fn pack/unpack helpers ----------------
#if __has_builtin(__builtin_amdgcn_cvt_pk_fp8_f32)
template<bool HIW>
__device__ inline u32 pk_fp8(float a, float b, u32 old){
  return (u32)__builtin_amdgcn_cvt_pk_fp8_f32(a, b, (int)old, HIW);
}
#else
__device__ inline u8 f2fp8_1(float f){
  union{float f; u32 u;} v; v.f = f;
  u32 s = (v.u >> 24) & 0x80u;
  u32 abs = v.u & 0x7fffffffu;
  if (abs < 0x3c800000u){
    float sc = fabsf(f) * 512.0f;
    int m = (int)rintf(sc);
    return (u8)(s | (u32)m);
  }
  u32 e8 = abs >> 23; u32 mant = abs & 0x7fffffu;
  u32 m3 = mant >> 20; u32 rest = mant & 0xfffffu;
  u32 rb = (rest > 0x80000u) || (rest == 0x80000u && (m3 & 1u));
  m3 += rb;
  u32 E = e8 - 120u;
  if (m3 == 8u){ m3 = 0u; E += 1u; }
  if (E >= 16u || (E == 15u && m3 == 7u)) return (u8)(s | 0x7Eu);
  return (u8)(s | (E << 3) | m3);
}
template<bool HIW>
__device__ inline u32 pk_fp8(float a, float b, u32 old){
  u32 w = (u32)f2fp8_1(a) | ((u32)f2fp8_1(b) << 8);
  return HIW ? ((old & 0x0000FFFFu) | (w << 16)) : ((old & 0xFFFF0000u) | w);
}
#endif

#if __has_builtin(__builtin_amdgcn_cvt_pk_f32_fp8)
__device__ inline void upk_fp8x4(u32 w, float* x){
  auto a0 = __builtin_amdgcn_cvt_pk_f32_fp8((int)w, false);
  auto a1 = __builtin_amdgcn_cvt_pk_f32_fp8((int)w, true);
  x[0] = a0[0]; x[1] = a0[1]; x[2] = a1[0]; x[3] = a1[1];
}
#else
__device__ inline float fp8_1(u32 byte){
  u32 s = (byte & 0x80u) << 24;
  u32 E = (byte >> 3) & 15u, M = byte & 7u;
  union{u32 u; float f;} v;
  if (E == 0){ v.f = (float)M * (1.0f/512.0f); v.u |= s; }
  else v.u = s | ((E + 120u) << 23) | (M << 20);
  return v.f;
}
__device__ inline void upk_fp8x4(u32 w, float* x){
  x[0] = fp8_1(w & 255u); x[1] = fp8_1((w >> 8) & 255u);
  x[2] = fp8_1((w >> 16) & 255u); x[3] = fp8_1(w >> 24);
}
#endif

// ---------------- weight prep ----------------
__global__ __launch_bounds__(256) void prep_w_k(const float* __restrict__ w2,
    const float* __restrict__ w1, u8* __restrict__ w2p, u16* __restrict__ w1p){
  int bidx = blockIdx.x;
  if (bidx < 25){
    int tap = bidx;
    int i = threadIdx.x;
    int oc = i >> 3, q = i & 7, ic0 = q * 4;
    float v[4];
    #pragma unroll
    for (int j = 0; j < 4; ++j)
      v[j] = (oc < MC && ic0 + j < MC) ? w2[(oc*MC + ic0 + j)*25 + tap] : 0.f;
    u32 w = pk_fp8<false>(v[0], v[1], 0u);
    w = pk_fp8<true>(v[2], v[3], w);
    *(u32*)(w2p + tap*1024 + oc*32 + q*4) = w;
  } else {
    for (int i = threadIdx.x; i < 1600; i += 256){
      int oc = i & 31; int t2 = i >> 5; int tap = t2 % 25; int c = t2 / 25;
      float v = (oc < MC) ? w1[(oc*2 + c)*25 + tap] : 0.f;
      w1p[(c*25 + tap)*32 + oc] = f2bf(v);
    }
  }
}

// ---------------- kernel 1: row norms + bf16 conversion ----------------
__global__ __launch_bounds__(256) void row_norms_k(const float* __restrict__ q, const float* __restrict__ k,
    float* __restrict__ qq, float* __restrict__ kk,
    u16* __restrict__ qb16, u16* __restrict__ kb16){
  int wave = blockIdx.x * 4 + (threadIdx.x >> 6);
  int lane = threadIdx.x & 63;
  const float* src; float* dst; u16* bdst; int row;
  if (wave < NB * TT) { src = q; dst = qq; bdst = qb16; row = wave; }
  else                { src = k; dst = kk; bdst = kb16; row = wave - NB * TT; }
  const float4* p = (const float4*)(src + (size_t)row * DK + lane * 12);
  u16* ob = bdst + (size_t)row * DK + lane * 12;
  float s = 0.f;
  #pragma unroll
  for (int t = 0; t < 3; ++t){
    float4 v = p[t];
    s += v.x*v.x + v.y*v.y + v.z*v.z + v.w*v.w;
    uint2 st; st.x = pack2bf(v.x, v.y); st.y = pack2bf(v.z, v.w);
    *(uint2*)(ob + t*4) = st;
  }
  #pragma unroll
  for (int o = 32; o; o >>= 1) s += __shfl_xor(s, o);
  if (lane == 0) dst[row] = s;
}

// ---------------- kernel 2: cdist via bf16 MFMA + P + mask ----------------
// grid (4 row-tiles, NB); block 256 = 4 waves; wave w owns cols w*32..+31
__global__ __launch_bounds__(256) void cdist_mfma_k(
    const u16* __restrict__ Qb16, const u16* __restrict__ Kb16,
    const float* __restrict__ qq, const float* __restrict__ kk,
    const int* __restrict__ qlen, const int* __restrict__ klen,
    const float* __restrict__ qR, const float* __restrict__ kR,
    float* __restrict__ Dout, u16* __restrict__ inb){
  __shared__ __align__(16) char qs[32 * 1536];    // [32 rows][768 k] bf16, swizzled
  __shared__ __align__(16) char ksm[128 * 256];   // [128 cols][128 k] bf16, swizzled
  int rt = blockIdx.x;
  int b  = blockIdx.y;
  int r0 = rt * 32;
  int tid = threadIdx.x;
  const u16* Qg = Qb16 + ((size_t)b * TT + r0) * DK;
  const u16* Kg = Kb16 + (size_t)b * TT * DK;
  // stage Q tile (48KB): 3072 x 16B
  for (int idx = tid; idx < 3072; idx += 256){
    int row = idx / 96, ch = idx - row * 96;
    uint4 v = *(const uint4*)(Qg + row * DK + ch * 8);
    *(uint4*)(qs + row * 1536 + ((ch * 16) ^ ((row & 7) << 4))) = v;
  }
  int lane = tid & 63, w = tid >> 6;
  int hi = lane >> 5, l31 = lane & 31;
  int col = w * 32 + l31;
  f32x16 acc;
  #pragma unroll
  for (int r = 0; r < 16; ++r) acc[r] = 0.f;
  for (int kc = 0; kc < DK; kc += 128){
    __syncthreads();
    // stage K chunk (32KB): 2048 x 16B
    for (int idx = tid; idx < 2048; idx += 256){
      int c = idx >> 4, j = idx & 15;
      uint4 v = *(const uint4*)(Kg + c * DK + kc + j * 8);
      *(uint4*)(ksm + c * 256 + ((j * 16) ^ ((c & 7) << 4))) = v;
    }
    __syncthreads();
    #pragma unroll
    for (int k8 = 0; k8 < 8; ++k8){
      bf16x8 a  = *(const bf16x8*)(qs  + l31 * 1536 + (((kc + k8*16 + hi*8) * 2) ^ ((l31 & 7) << 4)));
      bf16x8 bv = *(const bf16x8*)(ksm + col * 256  + (((k8*16 + hi*8) * 2) ^ ((col & 7) << 4)));
      acc = __builtin_amdgcn_mfma_f32_32x32x16_bf16(a, bv, acc, 0, 0, 0);
    }
  }
  int ql = qlen[b], kl = klen[b];
  float kkv = kk[b * TT + col];
  float krv = kR[b * TT + col];
  bool cm = col < kl;
  #pragma unroll
  for (int r = 0; r < 16; ++r){
    int row = r0 + (r & 3) + 8 * (r >> 2) + 4 * hi;
    float qqv = qq[b * TT + row];
    float sq = qqv + kkv - 2.f * acc[r];
    float d = sqrtf(fmaxf(sq, 1e-12f));
    bool m = (row < ql) && cm;
    float dm = m ? d : 0.f;
    float pm = m ? fabsf(qR[b * TT + row] - krv) : 0.f;
    Dout[(((size_t)b * TT + row) << 7) + col] = dm;
    inb[((size_t)b * 2 + 0) * (TT*TT) + (row << 7) + col] = f2bf(dm);
    inb[((size_t)b * 2 + 1) * (TT*TT) + (row << 7) + col] = f2bf(pm);
  }
}

// ---------------- conv1: 2ch -> 30ch 5x5, output fp8 [b][y][x][c32] ----------------
__global__ __launch_bounds__(256) void conv1_k(const u16* __restrict__ inb,
    const u16* __restrict__ w1p, const float* __restrict__ bias, u8* __restrict__ act1){
  __shared__ u16 ilds[2][12][40];
  __shared__ u16 wl[2][25][32];
  __shared__ float bl[32];
  int tile = blockIdx.x, bb = blockIdx.y;
  int x0 = (tile & 3) * 32, y0 = (tile >> 2) * 8;
  int tid = threadIdx.x;
  for (int i = tid; i < 2*12*36; i += 256){
    int c = i / 432; int r2 = i - c*432; int ly = r2 / 36; int lx = r2 - ly*36;
    int gy = y0 - 2 + ly, gx = x0 - 2 + lx;
    u16 v = 0;
    if ((unsigned)gy < 128u && (unsigned)gx < 128u)
      v = inb[((size_t)(bb*2 + c) << 14) + (gy << 7) + gx];
    ilds[c][ly][lx] = v;
  }
  for (int i = tid; i < 1600; i += 256) ((u16*)wl)[i] = w1p[i];
  if (tid < 32) bl[tid] = (tid < MC) ? bias[tid] : 0.f;
  __syncthreads();
  int ocg = tid & 3, x8 = (tid >> 2) & 7, ty = tid >> 5;
  float bv[8];
  #pragma unroll
  for (int o = 0; o < 8; ++o) bv[o] = bl[ocg*8 + o];
  float acc[4][8];
  #pragma unroll
  for (int k = 0; k < 4; ++k)
    #pragma unroll
    for (int o = 0; o < 8; ++o) acc[k][o] = bv[o];
  #pragma unroll
  for (int c = 0; c < 2; ++c){
    #pragma unroll
    for (int dy = 0; dy < 5; ++dy){
      int ly = ty + dy;
      const u16* ip = &ilds[c][ly][4*x8];
      uint2 u0 = *(const uint2*)ip;
      uint2 u1 = *(const uint2*)(ip + 4);
      float xv[8];
      unpack2(u0.x, xv[0], xv[1]); unpack2(u0.y, xv[2], xv[3]);
      unpack2(u1.x, xv[4], xv[5]); unpack2(u1.y, xv[6], xv[7]);
      #pragma unroll
      for (int dx = 0; dx < 5; ++dx){
        uint4 wv = *(const uint4*)&wl[c][dy*5+dx][ocg*8];
        float wf[8];
        unpack2(wv.x, wf[0], wf[1]); unpack2(wv.y, wf[2], wf[3]);
        unpack2(wv.z, wf[4], wf[5]); unpack2(wv.w, wf[6], wf[7]);
        #pragma unroll
        for (int k = 0; k < 4; ++k)
          #pragma unroll
          for (int o = 0; o < 8; ++o)
            acc[k][o] = fmaf(xv[k+dx], wf[o], acc[k][o]);
      }
    }
  }
  int y = y0 + ty;
  #pragma unroll
  for (int k = 0; k < 4; ++k){
    int x = x0 + 4*x8 + k;
    float r0 = fmaxf(acc[k][0], 0.f), r1 = fmaxf(acc[k][1], 0.f);
    float r2 = fmaxf(acc[k][2], 0.f), r3 = fmaxf(acc[k][3], 0.f);
    float r4 = fmaxf(acc[k][4], 0.f), r5 = fmaxf(acc[k][5], 0.f);
    float r6 = fmaxf(acc[k][6], 0.f), r7 = fmaxf(acc[k][7], 0.f);
    u32 w0 = pk_fp8<false>(r0, r1, 0u); w0 = pk_fp8<true>(r2, r3, w0);
    u32 w1 = pk_fp8<false>(r4, r5, 0u); w1 = pk_fp8<true>(r6, r7, w1);
    uint2 st; st.x = w0; st.y = w1;
    *(uint2*)(act1 + ((((size_t)(bb*128 + y)*128 + x) << 5) + ocg*8)) = st;
  }
}

// ---------------- conv2: 30->30 5x5 via fp8 MFMA, fp8 in / fp8 out ----------------
#define C2_IN_ROWB 4224                 // 132 px * 32 B
#define C2_IN_BYTES (12*C2_IN_ROWB)     // 50688
#define C2_W_OFF C2_IN_BYTES
#define C2_SMEM (C2_W_OFF + 25*1024)    // 76288

__global__ __launch_bounds__(512, 4) void conv2_mfma_k(
    const u8* __restrict__ act1, const u8* __restrict__ w2p,
    const float* __restrict__ bias, u8* __restrict__ act2){
  __shared__ __align__(16) char smem[C2_SMEM];
  int yg = blockIdx.x;          // 0..15
  int bb = blockIdx.y;
  int y0 = yg * 8;
  int tid = threadIdx.x;
  {
    const uint4* src = (const uint4*)w2p;
    uint4* dst = (uint4*)(smem + C2_W_OFF);
    for (int i = tid; i < 1600; i += 512) dst[i] = src[i];
  }
  for (int i = tid; i < 3168; i += 512){
    int r = i / 264; int t2 = i - r*264; int lx = t2 >> 1; int h = t2 & 1;
    int gy = y0 - 2 + r, gx = lx - 2;
    uint4 v = make_uint4(0,0,0,0);
    if ((unsigned)gy < 128u && (unsigned)gx < 128u)
      v = *(const uint4*)(act1 + ((((size_t)(bb*128 + gy)*128 + gx)) << 5) + (h << 4));
    *(uint4*)(smem + r*C2_IN_ROWB + (lx << 5) + (h << 4)) = v;
  }
  __syncthreads();
  int lane = tid & 63, w = tid >> 6;
  int hi = lane >> 5, l31 = lane & 31;
  int aBase = C2_W_OFF + (l31 << 5) + (hi << 4);
  int bBase = (l31 << 5) + (hi << 4);
  f32x16 acc[4];
  #pragma unroll
  for (int t = 0; t < 4; ++t)
    #pragma unroll
    for (int r = 0; r < 16; ++r) acc[t][r] = 0.f;
  #pragma unroll
  for (int dy = 0; dy < 5; ++dy){
    const char* rowp = smem + (w + dy)*C2_IN_ROWB + bBase;
    #pragma unroll
    for (int dx = 0; dx < 5; ++dx){
      ll2 a = *(const ll2*)(smem + aBase + (dy*5 + dx)*1024);
      #pragma unroll
      for (int t = 0; t < 4; ++t){
        ll2 b = *(const ll2*)(rowp + (t*32 + dx)*32);
        acc[t] = __builtin_amdgcn_mfma_f32_32x32x16_fp8_fp8(a.x, b.x, acc[t], 0, 0, 0);
        acc[t] = __builtin_amdgcn_mfma_f32_32x32x16_fp8_fp8(a.y, b.y, acc[t], 0, 0, 0);
      }
    }
  }
  float biasv[16];
  #pragma unroll
  for (int r = 0; r < 16; ++r){
    int oc = (r & 3) + 8*(r >> 2) + 4*hi;
    biasv[r] = (oc < MC) ? bias[oc] : 0.f;
  }
  __syncthreads();
  int wbase = w * 8192;
  #pragma unroll
  for (int t = 0; t < 4; ++t){
    int px = t*32 + l31;
    #pragma unroll
    for (int q = 0; q < 4; ++q){
      float v0 = fmaxf(acc[t][4*q+0] + biasv[4*q+0], 0.f);
      float v1 = fmaxf(acc[t][4*q+1] + biasv[4*q+1], 0.f);
      float v2 = fmaxf(acc[t][4*q+2] + biasv[4*q+2], 0.f);
      float v3 = fmaxf(acc[t][4*q+3] + biasv[4*q+3], 0.f);
      u32 word = pk_fp8<false>(v0, v1, 0u);
      word = pk_fp8<true>(v2, v3, word);
      int addr = wbase + (((px<<5) + (q<<3) + (hi<<2)) ^ ((px&7)<<3));
      *(u32*)(smem + addr) = word;
    }
  }
  int y = y0 + w;
  #pragma unroll
  for (int p = 0; p < 8; ++p){
    int x = p*16 + (lane >> 2), cg = lane & 3;
    int addr = wbase + (((x<<5) + (cg<<3)) ^ ((x&7)<<3));
    uint2 v = *(const uint2*)(smem + addr);
    *(uint2*)(act2 + ((((size_t)bb*128 + y)*128 + x) << 5) + cg*8) = v;
  }
}

// ---------------- conv3 + mask + row softmax + A write + row D*A ----------------
__global__ __launch_bounds__(512) void conv3sm_k(const u8* __restrict__ act2,
    const float* __restrict__ w3, const float* __restrict__ b3, const float* __restrict__ Dbuf,
    const int* __restrict__ qlen, const int* __restrict__ klen,
    float* __restrict__ Aout, float* __restrict__ rowsum, int b0){
  __shared__ float wlds[9][32];
  __shared__ float ex0[512], ex2[512];
  __shared__ float redm[8], reds[8], redd[8];
  int i  = blockIdx.x;
  int bb = blockIdx.y;
  int b  = b0 + bb;
  int tid = threadIdx.x;
  for (int idx = tid; idx < 288; idx += 512){
    int tap = idx >> 5, c = idx & 31;
    wlds[tap][c] = (c < MC) ? w3[c * 9 + tap] : 0.f;
  }
  __syncthreads();
  int px = tid >> 2, cg = tid & 3, wv = tid >> 6;
  float T0 = 0.f, T1 = 0.f, T2 = 0.f;
  #pragma unroll
  for (int dy = 0; dy < 3; ++dy){
    int gy = i - 1 + dy;
    uint2 v = make_uint2(0, 0);
    if ((unsigned)gy < 128u)
      v = *(const uint2*)(act2 + ((((size_t)bb*128 + gy)*128 + px) << 5) + cg*8);
    float x[8];
    upk_fp8x4(v.x, x);
    upk_fp8x4(v.y, x + 4);
    const float* w0p = &wlds[dy*3 + 0][cg*8];
    const float* w1p = &wlds[dy*3 + 1][cg*8];
    const float* w2q = &wlds[dy*3 + 2][cg*8];
    #pragma unroll
    for (int c = 0; c < 8; ++c){
      T0 = fmaf(x[c], w0p[c], T0);
      T1 = fmaf(x[c], w1p[c], T1);
      T2 = fmaf(x[c], w2q[c], T2);
    }
  }
  ex0[tid] = T0; ex2[tid] = T2;
  __syncthreads();
  float acc = T1;
  if (px > 0)   acc += ex0[tid - 4];
  if (px < 127) acc += ex2[tid + 4];
  acc += __shfl_xor(acc, 1);
  acc += __shfl_xor(acc, 2);
  acc += b3[0];
  float Dv = Dbuf[(((size_t)b * 128 + i) << 7) + px];
  bool m = (i < qlen[b]) && (px < klen[b]);
  float xv = m ? -(acc + Dv) : -100.f;
  float mx = xv;
  #pragma unroll
  for (int o = 32; o; o >>= 1) mx = fmaxf(mx, __shfl_xor(mx, o));
  if ((tid & 63) == 0) redm[wv] = mx;
  __syncthreads();
  mx = fmaxf(fmaxf(fmaxf(redm[0], redm[1]), fmaxf(redm[2], redm[3])),
             fmaxf(fmaxf(redm[4], redm[5]), fmaxf(redm[6], redm[7])));
  float e = __expf(xv - mx);
  float s  = e;
  float de = Dv * e;
  #pragma unroll
  for (int o = 32; o; o >>= 1){ s += __shfl_xor(s, o); de += __shfl_xor(de, o); }
  if ((tid & 63) == 0){ reds[wv] = s; redd[wv] = de; }
  __syncthreads();
  float s8  = (reds[0] + reds[1]) + (reds[2] + reds[3]) + (reds[4] + reds[5]) + (reds[6] + reds[7]);
  float a = e * 4.0f / s8;
  if (cg == 0) Aout[(((size_t)b * 128 + i) << 7) + px] = a;
  if (tid == 0){
    float d8 = (redd[0] + redd[1]) + (redd[2] + redd[3]) + (redd[4] + redd[5]) + (redd[6] + redd[7]);
    rowsum[b * TT + i] = d8 / s8;
  }
}

// ---------------- dis reduce ----------------
__global__ __launch_bounds__(128) void dis_k(const float* __restrict__ rowsum, float* __restrict__ out){
  int b = blockIdx.x, tid = threadIdx.x;
  float v = rowsum[b * TT + tid];
  #pragma unroll
  for (int o = 32; o; o >>= 1) v += __shfl_xor(v, o);
  __shared__ float red[2];
  if ((tid & 63) == 0) red[tid >> 6] = v;
  __syncthreads();
  if (tid == 0) out[b] = (red[0] + red[1]) * (1.0f / 128.0f);
}

extern "C" void kernel_launch(void* const* d_in, const int* in_sizes, int n_in,
                              void* d_out, int out_size, void* d_ws, size_t ws_size,
                              hipStream_t stream){
  const float* q_seq = (const float*)d_in[0];
  const int*   q_len = (const int*)d_in[1];
  const float* q_R   = (const float*)d_in[2];
  const float* k_seq = (const float*)d_in[3];
  const int*   k_len = (const int*)d_in[4];
  const float* k_R   = (const float*)d_in[5];
  const float* c1w   = (const float*)d_in[6];
  const float* c1b   = (const float*)d_in[7];
  const float* c2w   = (const float*)d_in[8];
  const float* c2b   = (const float*)d_in[9];
  const float* c3w   = (const float*)d_in[10];
  const float* c3b   = (const float*)d_in[11];
  float* out = (float*)d_out;

  char* base = (char*)d_ws;
  size_t off = 0;
  auto take = [&](size_t bytes)->char*{
    char* p = base + off;
    off = (off + bytes + 255) & ~(size_t)255;
    return p;
  };
  float* Dbuf   = (float*)take((size_t)NB * TT * TT * 4);
  float* qq     = (float*)take((size_t)NB * TT * 4);
  float* kkn    = (float*)take((size_t)NB * TT * 4);
  float* rowsum = (float*)take((size_t)NB * TT * 4);
  u16*   inb    = (u16*)  take((size_t)NB * 2 * TT * TT * 2);
  u8*    w2p    = (u8*)   take(25 * 1024);
  u16*   w1p    = (u16*)  take(1600 * 2);
  u16*   qb16   = (u16*)  take((size_t)NB * TT * DK * 2);
  u16*   kb16   = (u16*)  take((size_t)NB * TT * DK * 2);
  size_t fixed = off;
  int BCH = 64;
  while (BCH > 1 && fixed + (size_t)BCH * TT * TT * 64 + 1024 > ws_size) BCH >>= 1;
  u8* act1 = (u8*)take((size_t)BCH * TT * TT * 32);
  u8* act2 = (u8*)take((size_t)BCH * TT * TT * 32);

  prep_w_k<<<26, 256, 0, stream>>>(c2w, c1w, w2p, w1p);
  row_norms_k<<<4096, 256, 0, stream>>>(q_seq, k_seq, qq, kkn, qb16, kb16);
  cdist_mfma_k<<<dim3(4, NB), 256, 0, stream>>>(qb16, kb16, qq, kkn, q_len, k_len, q_R, k_R, Dbuf, inb);
  for (int b0 = 0; b0 < NB; b0 += BCH){
    int nb = BCH;
    conv1_k<<<dim3(64, nb), 256, 0, stream>>>(inb + (size_t)b0 * 2 * TT * TT, w1p, c1b, act1);
    conv2_mfma_k<<<dim3(16, nb), 512, 0, stream>>>(act1, w2p, c2b, act2);
    conv3sm_k<<<dim3(TT, nb), 512, 0, stream>>>(act2, c3w, c3b, Dbuf, q_len, k_len, out, rowsum, b0);
  }
  dis_k<<<NB, 128, 0, stream>>>(rowsum, out + (size_t)NB * TT * TT);
}

// Round 8
// 128.103 us; speedup vs baseline: 11.0058x; 1.2520x over previous
//
#include <hip/hip_runtime.h>
#include <hip/hip_bf16.h>
#include <stdint.h>

using u16 = unsigned short;
using u32 = unsigned int;
using u8  = unsigned char;

#define NB 64
#define TT 128
#define DK 768
#define MC 30

typedef float f32x16 __attribute__((ext_vector_type(16)));
typedef __bf16 bf16x8 __attribute__((ext_vector_type(8)));
typedef long long ll;
typedef __attribute__((ext_vector_type(2))) ll ll2;

__device__ inline void unpack2(u32 u, float& lo, float& hi){
  union{u32 i; float f;} a, b; a.i = u << 16; b.i = u & 0xFFFF0000u; lo = a.f; hi = b.f;
}
__device__ inline u16 f2bf(float f){
  union{u32 i; float f;} v; v.f = f;
  u32 r = v.i + 0x7FFFu + ((v.i >> 16) & 1u);
  return (u16)(r >> 16);
}
__device__ inline u32 pack2bf(float a, float b){ return (u32)f2bf(a) | ((u32)f2bf(b) << 16); }

// ---------------- fp8 e4m3fn pack/unpack helpers ----------------
#if __has_builtin(__builtin_amdgcn_cvt_pk_fp8_f32)
template<bool HIW>
__device__ inline u32 pk_fp8(float a, float b, u32 old){
  return (u32)__builtin_amdgcn_cvt_pk_fp8_f32(a, b, (int)old, HIW);
}
#else
__device__ inline u8 f2fp8_1(float f){
  union{float f; u32 u;} v; v.f = f;
  u32 s = (v.u >> 24) & 0x80u;
  u32 abs = v.u & 0x7fffffffu;
  if (abs < 0x3c800000u){
    float sc = fabsf(f) * 512.0f;
    int m = (int)rintf(sc);
    return (u8)(s | (u32)m);
  }
  u32 e8 = abs >> 23; u32 mant = abs & 0x7fffffu;
  u32 m3 = mant >> 20; u32 rest = mant & 0xfffffu;
  u32 rb = (rest > 0x80000u) || (rest == 0x80000u && (m3 & 1u));
  m3 += rb;
  u32 E = e8 - 120u;
  if (m3 == 8u){ m3 = 0u; E += 1u; }
  if (E >= 16u || (E == 15u && m3 == 7u)) return (u8)(s | 0x7Eu);
  return (u8)(s | (E << 3) | m3);
}
template<bool HIW>
__device__ inline u32 pk_fp8(float a, float b, u32 old){
  u32 w = (u32)f2fp8_1(a) | ((u32)f2fp8_1(b) << 8);
  return HIW ? ((old & 0x0000FFFFu) | (w << 16)) : ((old & 0xFFFF0000u) | w);
}
#endif

#if __has_builtin(__builtin_amdgcn_cvt_pk_f32_fp8)
__device__ inline void upk_fp8x4(u32 w, float* x){
  auto a0 = __builtin_amdgcn_cvt_pk_f32_fp8((int)w, false);
  auto a1 = __builtin_amdgcn_cvt_pk_f32_fp8((int)w, true);
  x[0] = a0[0]; x[1] = a0[1]; x[2] = a1[0]; x[3] = a1[1];
}
#else
__device__ inline float fp8_1(u32 byte){
  u32 s = (byte & 0x80u) << 24;
  u32 E = (byte >> 3) & 15u, M = byte & 7u;
  union{u32 u; float f;} v;
  if (E == 0){ v.f = (float)M * (1.0f/512.0f); v.u |= s; }
  else v.u = s | ((E + 120u) << 23) | (M << 20);
  return v.f;
}
__device__ inline void upk_fp8x4(u32 w, float* x){
  x[0] = fp8_1(w & 255u); x[1] = fp8_1((w >> 8) & 255u);
  x[2] = fp8_1((w >> 16) & 255u); x[3] = fp8_1(w >> 24);
}
#endif

// ---------------- weight prep ----------------
// w2p: fp8 [tap][oc32][ic32] linear, 1024 B per tap
// w1c: bf16 MFMA A-frag table [dy][oc32][k16], k = dx*2 + c (dx>=5 zero), swizzled
__global__ __launch_bounds__(256) void prep_w_k(const float* __restrict__ w2,
    const float* __restrict__ w1, u8* __restrict__ w2p, u16* __restrict__ w1c){
  int bidx = blockIdx.x;
  if (bidx < 25){
    int tap = bidx;
    int i = threadIdx.x;
    int oc = i >> 3, q = i & 7, ic0 = q * 4;
    float v[4];
    #pragma unroll
    for (int j = 0; j < 4; ++j)
      v[j] = (oc < MC && ic0 + j < MC) ? w2[(oc*MC + ic0 + j)*25 + tap] : 0.f;
    u32 w = pk_fp8<false>(v[0], v[1], 0u);
    w = pk_fp8<true>(v[2], v[3], w);
    *(u32*)(w2p + tap*1024 + oc*32 + q*4) = w;
  } else {
    for (int i = threadIdx.x; i < 2560; i += 256){
      int dy = i >> 9; int rem = i & 511; int oc = rem >> 4; int k = rem & 15;
      int dx = k >> 1, c = k & 1;
      float v = (oc < MC && dx < 5) ? w1[(oc*2 + c)*25 + dy*5 + dx] : 0.f;
      int byteoff = dy*1024 + (((oc<<5) + (k<<1)) ^ ((oc&7)<<4));
      *(u16*)((char*)w1c + byteoff) = f2bf(v);
    }
  }
}

// ---------------- kernel 1: row norms + bf16 conversion ----------------
__global__ __launch_bounds__(256) void row_norms_k(const float* __restrict__ q, const float* __restrict__ k,
    float* __restrict__ qq, float* __restrict__ kk,
    u16* __restrict__ qb16, u16* __restrict__ kb16){
  int wave = blockIdx.x * 4 + (threadIdx.x >> 6);
  int lane = threadIdx.x & 63;
  const float* src; float* dst; u16* bdst; int row;
  if (wave < NB * TT) { src = q; dst = qq; bdst = qb16; row = wave; }
  else                { src = k; dst = kk; bdst = kb16; row = wave - NB * TT; }
  const float4* p = (const float4*)(src + (size_t)row * DK + lane * 12);
  u16* ob = bdst + (size_t)row * DK + lane * 12;
  float s = 0.f;
  #pragma unroll
  for (int t = 0; t < 3; ++t){
    float4 v = p[t];
    s += v.x*v.x + v.y*v.y + v.z*v.z + v.w*v.w;
    uint2 st; st.x = pack2bf(v.x, v.y); st.y = pack2bf(v.z, v.w);
    *(uint2*)(ob + t*4) = st;
  }
  #pragma unroll
  for (int o = 32; o; o >>= 1) s += __shfl_xor(s, o);
  if (lane == 0) dst[row] = s;
}

// ---------------- kernel 2: cdist via bf16 MFMA + P + mask ----------------
// inb output: u32 per (b,y,x): lo = bf16(D), hi = bf16(P)
__global__ __launch_bounds__(256) void cdist_mfma_k(
    const u16* __restrict__ Qb16, const u16* __restrict__ Kb16,
    const float* __restrict__ qq, const float* __restrict__ kk,
    const int* __restrict__ qlen, const int* __restrict__ klen,
    const float* __restrict__ qR, const float* __restrict__ kR,
    float* __restrict__ Dout, u32* __restrict__ inb){
  __shared__ __align__(16) char qs[32 * 1536];    // [32 rows][768 k] bf16, swizzled
  __shared__ __align__(16) char ksm[128 * 256];   // [128 cols][128 k] bf16, swizzled
  int rt = blockIdx.x;
  int b  = blockIdx.y;
  int r0 = rt * 32;
  int tid = threadIdx.x;
  const u16* Qg = Qb16 + ((size_t)b * TT + r0) * DK;
  const u16* Kg = Kb16 + (size_t)b * TT * DK;
  for (int idx = tid; idx < 3072; idx += 256){
    int row = idx / 96, ch = idx - row * 96;
    uint4 v = *(const uint4*)(Qg + row * DK + ch * 8);
    *(uint4*)(qs + row * 1536 + ((ch * 16) ^ ((row & 7) << 4))) = v;
  }
  int lane = tid & 63, w = tid >> 6;
  int hi = lane >> 5, l31 = lane & 31;
  int col = w * 32 + l31;
  f32x16 acc;
  #pragma unroll
  for (int r = 0; r < 16; ++r) acc[r] = 0.f;
  for (int kc = 0; kc < DK; kc += 128){
    __syncthreads();
    for (int idx = tid; idx < 2048; idx += 256){
      int c = idx >> 4, j = idx & 15;
      uint4 v = *(const uint4*)(Kg + c * DK + kc + j * 8);
      *(uint4*)(ksm + c * 256 + ((j * 16) ^ ((c & 7) << 4))) = v;
    }
    __syncthreads();
    #pragma unroll
    for (int k8 = 0; k8 < 8; ++k8){
      bf16x8 a  = *(const bf16x8*)(qs  + l31 * 1536 + (((kc + k8*16 + hi*8) * 2) ^ ((l31 & 7) << 4)));
      bf16x8 bv = *(const bf16x8*)(ksm + col * 256  + (((k8*16 + hi*8) * 2) ^ ((col & 7) << 4)));
      acc = __builtin_amdgcn_mfma_f32_32x32x16_bf16(a, bv, acc, 0, 0, 0);
    }
  }
  int ql = qlen[b], kl = klen[b];
  float kkv = kk[b * TT + col];
  float krv = kR[b * TT + col];
  bool cm = col < kl;
  #pragma unroll
  for (int r = 0; r < 16; ++r){
    int row = r0 + (r & 3) + 8 * (r >> 2) + 4 * hi;
    float qqv = qq[b * TT + row];
    float sq = qqv + kkv - 2.f * acc[r];
    float d = sqrtf(fmaxf(sq, 1e-12f));
    bool m = (row < ql) && cm;
    float dm = m ? d : 0.f;
    float pm = m ? fabsf(qR[b * TT + row] - krv) : 0.f;
    Dout[(((size_t)b * TT + row) << 7) + col] = dm;
    inb[(((size_t)b * TT + row) << 7) + col] = pack2bf(dm, pm);
  }
}

// ---------------- conv1: 2ch -> 30ch 5x5 via bf16 MFMA, fp8 out [b][y][x][c32] ----------------
// K=16 slice per dy: k = dx*2 + c, dx in [0,8) (5..7 zero-padded weights)
#define C1_ROWW 136
__global__ __launch_bounds__(512, 2) void conv1_mfma_k(const u32* __restrict__ inb,
    const u16* __restrict__ w1c, const float* __restrict__ bias, u8* __restrict__ act1){
  __shared__ u32 ilds[12 * C1_ROWW];
  __shared__ __align__(16) char wlds[5120];
  __shared__ __align__(16) char tr[8 * 4096];
  int yg = blockIdx.x, bb = blockIdx.y;
  int y0 = yg * 8, tid = threadIdx.x;
  {
    const uint4* src = (const uint4*)w1c;
    uint4* dst = (uint4*)wlds;
    for (int i = tid; i < 320; i += 512) dst[i] = src[i];
  }
  for (int i = tid; i < 12 * C1_ROWW; i += 512){
    int r = i / C1_ROWW, xi = i - r * C1_ROWW;
    int gy = y0 - 2 + r, gx = xi - 2;
    u32 v = 0;
    if ((unsigned)gy < 128u && (unsigned)gx < 128u)
      v = inb[(((size_t)bb * 128 + gy) << 7) + gx];
    ilds[r * C1_ROWW + xi] = v;
  }
  __syncthreads();
  int lane = tid & 63, w = tid >> 6;
  int hi = lane >> 5, l31 = lane & 31;
  bf16x8 afr[5];
  #pragma unroll
  for (int dy = 0; dy < 5; ++dy)
    afr[dy] = *(const bf16x8*)(wlds + dy*1024 + (((l31<<5) + (hi<<4)) ^ ((l31&7)<<4)));
  float biasv[16];
  #pragma unroll
  for (int r = 0; r < 16; ++r){
    int oc = (r & 3) + 8*(r >> 2) + 4*hi;
    biasv[r] = (oc < MC) ? bias[oc] : 0.f;
  }
  int wbase = w * 4096;
  #pragma unroll
  for (int t = 0; t < 4; ++t){
    int px = t*32 + l31;
    f32x16 acc;
    #pragma unroll
    for (int r = 0; r < 16; ++r) acc[r] = 0.f;
    #pragma unroll
    for (int dy = 0; dy < 5; ++dy){
      const u32* rp = &ilds[(w + dy)*C1_ROWW + px + hi*4];
      union { u32 uw[4]; bf16x8 v; } ub;
      ub.uw[0] = rp[0]; ub.uw[1] = rp[1]; ub.uw[2] = rp[2]; ub.uw[3] = rp[3];
      acc = __builtin_amdgcn_mfma_f32_32x32x16_bf16(afr[dy], ub.v, acc, 0, 0, 0);
    }
    #pragma unroll
    for (int q = 0; q < 4; ++q){
      float v0 = fmaxf(acc[4*q+0] + biasv[4*q+0], 0.f);
      float v1 = fmaxf(acc[4*q+1] + biasv[4*q+1], 0.f);
      float v2 = fmaxf(acc[4*q+2] + biasv[4*q+2], 0.f);
      float v3 = fmaxf(acc[4*q+3] + biasv[4*q+3], 0.f);
      u32 word = pk_fp8<false>(v0, v1, 0u);
      word = pk_fp8<true>(v2, v3, word);
      int addr = wbase + (((px<<5) + (q<<3) + (hi<<2)) ^ ((px&7)<<3));
      *(u32*)(tr + addr) = word;
    }
  }
  int y = y0 + w;
  #pragma unroll
  for (int p = 0; p < 8; ++p){
    int x = p*16 + (lane >> 2), cg = lane & 3;
    int addr = wbase + (((x<<5) + (cg<<3)) ^ ((x&7)<<3));
    uint2 v = *(const uint2*)(tr + addr);
    *(uint2*)(act1 + ((((size_t)bb*128 + y)*128 + x) << 5) + cg*8) = v;
  }
}

// ---------------- conv2: 30->30 5x5 via fp8 MFMA, fp8 in / fp8 out ----------------
#define C2_IN_ROWB 4224                 // 132 px * 32 B
#define C2_IN_BYTES (12*C2_IN_ROWB)     // 50688
#define C2_W_OFF C2_IN_BYTES
#define C2_SMEM (C2_W_OFF + 25*1024)    // 76288

__global__ __launch_bounds__(512, 4) void conv2_mfma_k(
    const u8* __restrict__ act1, const u8* __restrict__ w2p,
    const float* __restrict__ bias, u8* __restrict__ act2){
  __shared__ __align__(16) char smem[C2_SMEM];
  int yg = blockIdx.x;          // 0..15
  int bb = blockIdx.y;
  int y0 = yg * 8;
  int tid = threadIdx.x;
  {
    const uint4* src = (const uint4*)w2p;
    uint4* dst = (uint4*)(smem + C2_W_OFF);
    for (int i = tid; i < 1600; i += 512) dst[i] = src[i];
  }
  for (int i = tid; i < 3168; i += 512){
    int r = i / 264; int t2 = i - r*264; int lx = t2 >> 1; int h = t2 & 1;
    int gy = y0 - 2 + r, gx = lx - 2;
    uint4 v = make_uint4(0,0,0,0);
    if ((unsigned)gy < 128u && (unsigned)gx < 128u)
      v = *(const uint4*)(act1 + ((((size_t)(bb*128 + gy)*128 + gx)) << 5) + (h << 4));
    *(uint4*)(smem + r*C2_IN_ROWB + (lx << 5) + (h << 4)) = v;
  }
  __syncthreads();
  int lane = tid & 63, w = tid >> 6;
  int hi = lane >> 5, l31 = lane & 31;
  int aBase = C2_W_OFF + (l31 << 5) + (hi << 4);
  int bBase = (l31 << 5) + (hi << 4);
  f32x16 acc[4];
  #pragma unroll
  for (int t = 0; t < 4; ++t)
    #pragma unroll
    for (int r = 0; r < 16; ++r) acc[t][r] = 0.f;
  #pragma unroll
  for (int dy = 0; dy < 5; ++dy){
    const char* rowp = smem + (w + dy)*C2_IN_ROWB + bBase;
    #pragma unroll
    for (int dx = 0; dx < 5; ++dx){
      ll2 a = *(const ll2*)(smem + aBase + (dy*5 + dx)*1024);
      #pragma unroll
      for (int t = 0; t < 4; ++t){
        ll2 b = *(const ll2*)(rowp + (t*32 + dx)*32);
        acc[t] = __builtin_amdgcn_mfma_f32_32x32x16_fp8_fp8(a.x, b.x, acc[t], 0, 0, 0);
        acc[t] = __builtin_amdgcn_mfma_f32_32x32x16_fp8_fp8(a.y, b.y, acc[t], 0, 0, 0);
      }
    }
  }
  float biasv[16];
  #pragma unroll
  for (int r = 0; r < 16; ++r){
    int oc = (r & 3) + 8*(r >> 2) + 4*hi;
    biasv[r] = (oc < MC) ? bias[oc] : 0.f;
  }
  __syncthreads();
  int wbase = w * 8192;
  #pragma unroll
  for (int t = 0; t < 4; ++t){
    int px = t*32 + l31;
    #pragma unroll
    for (int q = 0; q < 4; ++q){
      float v0 = fmaxf(acc[t][4*q+0] + biasv[4*q+0], 0.f);
      float v1 = fmaxf(acc[t][4*q+1] + biasv[4*q+1], 0.f);
      float v2 = fmaxf(acc[t][4*q+2] + biasv[4*q+2], 0.f);
      float v3 = fmaxf(acc[t][4*q+3] + biasv[4*q+3], 0.f);
      u32 word = pk_fp8<false>(v0, v1, 0u);
      word = pk_fp8<true>(v2, v3, word);
      int addr = wbase + (((px<<5) + (q<<3) + (hi<<2)) ^ ((px&7)<<3));
      *(u32*)(smem + addr) = word;
    }
  }
  int y = y0 + w;
  #pragma unroll
  for (int p = 0; p < 8; ++p){
    int x = p*16 + (lane >> 2), cg = lane & 3;
    int addr = wbase + (((x<<5) + (cg<<3)) ^ ((x&7)<<3));
    uint2 v = *(const uint2*)(smem + addr);
    *(uint2*)(act2 + ((((size_t)bb*128 + y)*128 + x) << 5) + cg*8) = v;
  }
}

// ---------------- conv3 + mask + row softmax + A write + row D*A ----------------
__global__ __launch_bounds__(512) void conv3sm_k(const u8* __restrict__ act2,
    const float* __restrict__ w3, const float* __restrict__ b3, const float* __restrict__ Dbuf,
    const int* __restrict__ qlen, const int* __restrict__ klen,
    float* __restrict__ Aout, float* __restrict__ rowsum, int b0){
  __shared__ float wlds[9][32];
  __shared__ float ex0[512], ex2[512];
  __shared__ float redm[8], reds[8], redd[8];
  int i  = blockIdx.x;
  int bb = blockIdx.y;
  int b  = b0 + bb;
  int tid = threadIdx.x;
  for (int idx = tid; idx < 288; idx += 512){
    int tap = idx >> 5, c = idx & 31;
    wlds[tap][c] = (c < MC) ? w3[c * 9 + tap] : 0.f;
  }
  __syncthreads();
  int px = tid >> 2, cg = tid & 3, wv = tid >> 6;
  float T0 = 0.f, T1 = 0.f, T2 = 0.f;
  #pragma unroll
  for (int dy = 0; dy < 3; ++dy){
    int gy = i - 1 + dy;
    uint2 v = make_uint2(0, 0);
    if ((unsigned)gy < 128u)
      v = *(const uint2*)(act2 + ((((size_t)bb*128 + gy)*128 + px) << 5) + cg*8);
    float x[8];
    upk_fp8x4(v.x, x);
    upk_fp8x4(v.y, x + 4);
    const float* w0p = &wlds[dy*3 + 0][cg*8];
    const float* w1p = &wlds[dy*3 + 1][cg*8];
    const float* w2q = &wlds[dy*3 + 2][cg*8];
    #pragma unroll
    for (int c = 0; c < 8; ++c){
      T0 = fmaf(x[c], w0p[c], T0);
      T1 = fmaf(x[c], w1p[c], T1);
      T2 = fmaf(x[c], w2q[c], T2);
    }
  }
  ex0[tid] = T0; ex2[tid] = T2;
  __syncthreads();
  float acc = T1;
  if (px > 0)   acc += ex0[tid - 4];
  if (px < 127) acc += ex2[tid + 4];
  acc += __shfl_xor(acc, 1);
  acc += __shfl_xor(acc, 2);
  acc += b3[0];
  float Dv = Dbuf[(((size_t)b * 128 + i) << 7) + px];
  bool m = (i < qlen[b]) && (px < klen[b]);
  float xv = m ? -(acc + Dv) : -100.f;
  float mx = xv;
  #pragma unroll
  for (int o = 32; o; o >>= 1) mx = fmaxf(mx, __shfl_xor(mx, o));
  if ((tid & 63) == 0) redm[wv] = mx;
  __syncthreads();
  mx = fmaxf(fmaxf(fmaxf(redm[0], redm[1]), fmaxf(redm[2], redm[3])),
             fmaxf(fmaxf(redm[4], redm[5]), fmaxf(redm[6], redm[7])));
  float e = __expf(xv - mx);
  float s  = e;
  float de = Dv * e;
  #pragma unroll
  for (int o = 32; o; o >>= 1){ s += __shfl_xor(s, o); de += __shfl_xor(de, o); }
  if ((tid & 63) == 0){ reds[wv] = s; redd[wv] = de; }
  __syncthreads();
  float s8  = (reds[0] + reds[1]) + (reds[2] + reds[3]) + (reds[4] + reds[5]) + (reds[6] + reds[7]);
  float a = e * 4.0f / s8;
  if (cg == 0) Aout[(((size_t)b * 128 + i) << 7) + px] = a;
  if (tid == 0){
    float d8 = (redd[0] + redd[1]) + (redd[2] + redd[3]) + (redd[4] + redd[5]) + (redd[6] + redd[7]);
    rowsum[b * TT + i] = d8 / s8;
  }
}

// ---------------- dis reduce ----------------
__global__ __launch_bounds__(128) void dis_k(const float* __restrict__ rowsum, float* __restrict__ out){
  int b = blockIdx.x, tid = threadIdx.x;
  float v = rowsum[b * TT + tid];
  #pragma unroll
  for (int o = 32; o; o >>= 1) v += __shfl_xor(v, o);
  __shared__ float red[2];
  if ((tid & 63) == 0) red[tid >> 6] = v;
  __syncthreads();
  if (tid == 0) out[b] = (red[0] + red[1]) * (1.0f / 128.0f);
}

extern "C" void kernel_launch(void* const* d_in, const int* in_sizes, int n_in,
                              void* d_out, int out_size, void* d_ws, size_t ws_size,
                              hipStream_t stream){
  const float* q_seq = (const float*)d_in[0];
  const int*   q_len = (const int*)d_in[1];
  const float* q_R   = (const float*)d_in[2];
  const float* k_seq = (const float*)d_in[3];
  const int*   k_len = (const int*)d_in[4];
  const float* k_R   = (const float*)d_in[5];
  const float* c1w   = (const float*)d_in[6];
  const float* c1b   = (const float*)d_in[7];
  const float* c2w   = (const float*)d_in[8];
  const float* c2b   = (const float*)d_in[9];
  const float* c3w   = (const float*)d_in[10];
  const float* c3b   = (const float*)d_in[11];
  float* out = (float*)d_out;

  char* base = (char*)d_ws;
  size_t off = 0;
  auto take = [&](size_t bytes)->char*{
    char* p = base + off;
    off = (off + bytes + 255) & ~(size_t)255;
    return p;
  };
  float* Dbuf   = (float*)take((size_t)NB * TT * TT * 4);
  float* qq     = (float*)take((size_t)NB * TT * 4);
  float* kkn    = (float*)take((size_t)NB * TT * 4);
  float* rowsum = (float*)take((size_t)NB * TT * 4);
  u32*   inb    = (u32*)  take((size_t)NB * TT * TT * 4);
  u8*    w2p    = (u8*)   take(25 * 1024);
  u16*   w1c    = (u16*)  take(5 * 1024);
  u16*   qb16   = (u16*)  take((size_t)NB * TT * DK * 2);
  u16*   kb16   = (u16*)  take((size_t)NB * TT * DK * 2);
  size_t fixed = off;
  int BCH = 64;
  while (BCH > 1 && fixed + (size_t)BCH * TT * TT * 64 + 1024 > ws_size) BCH >>= 1;
  u8* act1 = (u8*)take((size_t)BCH * TT * TT * 32);
  u8* act2 = (u8*)take((size_t)BCH * TT * TT * 32);

  prep_w_k<<<26, 256, 0, stream>>>(c2w, c1w, w2p, w1c);
  row_norms_k<<<4096, 256, 0, stream>>>(q_seq, k_seq, qq, kkn, qb16, kb16);
  cdist_mfma_k<<<dim3(4, NB), 256, 0, stream>>>(qb16, kb16, qq, kkn, q_len, k_len, q_R, k_R, Dbuf, inb);
  for (int b0 = 0; b0 < NB; b0 += BCH){
    int nb = BCH;
    conv1_mfma_k<<<dim3(16, nb), 512, 0, stream>>>(inb + (size_t)b0 * TT * TT, w1c, c1b, act1);
    conv2_mfma_k<<<dim3(16, nb), 512, 0, stream>>>(act1, w2p, c2b, act2);
    conv3sm_k<<<dim3(TT, nb), 512, 0, stream>>>(act2, c3w, c3b, Dbuf, q_len, k_len, out, rowsum, b0);
  }
  dis_k<<<NB, 128, 0, stream>>>(rowsum, out + (size_t)NB * TT * TT);
}